// Round 2
// baseline (268.932 us; speedup 1.0000x reference)
//
#include <hip/hip_runtime.h>
#include <hip/hip_bf16.h>

#define D_MODEL 1024
#define HEADS 16
#define HSZ 64
#define BATCH 2
#define SEQ 2048
#define TOK (BATCH*SEQ)   // 4096

typedef __attribute__((ext_vector_type(8))) short bf16x8;
typedef __attribute__((ext_vector_type(4))) float f32x4;

static __device__ __forceinline__ unsigned short f2bf(float f) {
  union { float f; unsigned u; } v; v.f = f;
  unsigned r = v.u + 0x7fffu + ((v.u >> 16) & 1u);
  return (unsigned short)(r >> 16);
}

// byte-offset swizzles: row-major LDS tiles, XOR row bits into the 16B-slot bits
static __device__ __forceinline__ int swz64(int row, int g) {   // 64B rows, g = 16B group
  return ((row << 6) + (g << 4)) ^ ((row & 7) << 4);
}
static __device__ __forceinline__ int swz128(int row, int g) {  // 128B rows
  return ((row << 7) + (g << 4)) ^ ((row & 7) << 4);
}

// ---------------- converts ----------------

__global__ void cvt_bf16_kernel(const float* __restrict__ src,
                                unsigned short* __restrict__ dst, int n) {
  int i = (blockIdx.x * blockDim.x + threadIdx.x) * 4;
  if (i >= n) return;
  float4 v = *reinterpret_cast<const float4*>(src + i);
  ushort4 o;
  o.x = f2bf(v.x); o.y = f2bf(v.y); o.z = f2bf(v.z); o.w = f2bf(v.w);
  *reinterpret_cast<ushort4*>(dst + i) = o;
}

// W[i][o] fp32 -> Wt[o][i] bf16 (k-contiguous for MFMA B-fragments).
// z = 0..2: Wq/Wk/Wv into Wqkvt (3072x1024); z = 3: Wo into Wot.
__global__ void transpose_cvt_kernel(const float* __restrict__ Wq, const float* __restrict__ Wk,
                                     const float* __restrict__ Wv, const float* __restrict__ Wo,
                                     unsigned short* __restrict__ Wqkvt,
                                     unsigned short* __restrict__ Wot) {
  __shared__ float tile[32][33];
  int m = blockIdx.z;
  const float* src = (m == 0) ? Wq : (m == 1) ? Wk : (m == 2) ? Wv : Wo;
  unsigned short* dst = (m < 3) ? (Wqkvt + (size_t)m * D_MODEL * D_MODEL) : Wot;
  int i0 = blockIdx.y * 32, o0 = blockIdx.x * 32;
  int tx = threadIdx.x, ty = threadIdx.y;
  for (int k = 0; k < 32; k += 8)
    tile[ty + k][tx] = src[(size_t)(i0 + ty + k) * D_MODEL + o0 + tx];
  __syncthreads();
  for (int k = 0; k < 32; k += 8)
    dst[(size_t)(o0 + ty + k) * D_MODEL + i0 + tx] = f2bf(tile[tx][ty + k]);
}

// ---------------- 128x128 bf16 GEMM, C = A[M,K] @ Bt[N,K]^T ----------------
// EPI 0: QKV epilogue (bias + scatter to Q/K/Vt bf16). EPI 1: fp32 out + bias.

template<int EPI>
__global__ __launch_bounds__(256) void gemm128_kernel(
    const unsigned short* __restrict__ A, const unsigned short* __restrict__ Bt,
    int K, int N,
    const float* __restrict__ b0, const float* __restrict__ b1, const float* __restrict__ b2,
    unsigned short* __restrict__ Qb, unsigned short* __restrict__ Kb,
    unsigned short* __restrict__ Vtb, float* __restrict__ Cout)
{
  __shared__ char As[128 * 64];   // 128 rows x 32 bf16, swizzled
  __shared__ char Bs[128 * 64];
  int m0 = blockIdx.y * 128, n0 = blockIdx.x * 128;
  int tid = threadIdx.x;
  int w = tid >> 6, l = tid & 63;
  int wm = w >> 1, wn = w & 1;
  int lg = l >> 4, lr = l & 15;
  int srow = tid >> 2, sg = tid & 3;

  f32x4 acc[4][4];
#pragma unroll
  for (int i = 0; i < 4; i++)
#pragma unroll
    for (int j = 0; j < 4; j++) acc[i][j] = (f32x4){0.f, 0.f, 0.f, 0.f};

  for (int k0 = 0; k0 < K; k0 += 32) {
    uint4 a0  = *reinterpret_cast<const uint4*>(A  + (size_t)(m0 + srow)      * K + k0 + sg * 8);
    uint4 a1  = *reinterpret_cast<const uint4*>(A  + (size_t)(m0 + srow + 64) * K + k0 + sg * 8);
    uint4 bb0 = *reinterpret_cast<const uint4*>(Bt + (size_t)(n0 + srow)      * K + k0 + sg * 8);
    uint4 bb1 = *reinterpret_cast<const uint4*>(Bt + (size_t)(n0 + srow + 64) * K + k0 + sg * 8);
    __syncthreads();   // previous iter's fragment reads done
    *reinterpret_cast<uint4*>(As + swz64(srow,      sg)) = a0;
    *reinterpret_cast<uint4*>(As + swz64(srow + 64, sg)) = a1;
    *reinterpret_cast<uint4*>(Bs + swz64(srow,      sg)) = bb0;
    *reinterpret_cast<uint4*>(Bs + swz64(srow + 64, sg)) = bb1;
    __syncthreads();

    bf16x8 af[4], bfv[4];
#pragma unroll
    for (int mi = 0; mi < 4; mi++)
      af[mi] = *reinterpret_cast<const bf16x8*>(As + swz64(wm * 64 + mi * 16 + lr, lg));
#pragma unroll
    for (int ni = 0; ni < 4; ni++)
      bfv[ni] = *reinterpret_cast<const bf16x8*>(Bs + swz64(wn * 64 + ni * 16 + lr, lg));
#pragma unroll
    for (int mi = 0; mi < 4; mi++)
#pragma unroll
      for (int ni = 0; ni < 4; ni++)
        acc[mi][ni] = __builtin_amdgcn_mfma_f32_16x16x32_bf16(af[mi], bfv[ni], acc[mi][ni], 0, 0, 0);
  }

  // epilogue: D frag mapping col = lane&15, row = (lane>>4)*4 + r
#pragma unroll
  for (int mi = 0; mi < 4; mi++) {
    int gr0 = m0 + wm * 64 + mi * 16 + lg * 4;
#pragma unroll
    for (int ni = 0; ni < 4; ni++) {
      int gc = n0 + wn * 64 + ni * 16 + lr;
      if (EPI == 0) {
        int mat = gc >> 10, o = gc & 1023;
        int hh = o >> 6, d = o & 63;
        const float* bias = (mat == 0) ? b0 : (mat == 1) ? b1 : b2;
        float bv = bias[o];
#pragma unroll
        for (int r = 0; r < 4; r++) {
          int t = gr0 + r;
          int b = t >> 11, s = t & 2047;
          unsigned short u = f2bf(acc[mi][ni][r] + bv);
          size_t head = (size_t)(b * HEADS + hh);
          if (mat == 0)      Qb [(head * SEQ + s) * HSZ + d] = u;
          else if (mat == 1) Kb [(head * SEQ + s) * HSZ + d] = u;
          else               Vtb[(head * HSZ + d) * SEQ + s] = u;   // V transposed
        }
      } else {
        float bv = b0[gc];
#pragma unroll
        for (int r = 0; r < 4; r++) {
          int t = gr0 + r;
          Cout[(size_t)t * N + gc] = acc[mi][ni][r] + bv;
        }
      }
    }
  }
}

// ---------------- flash attention ----------------
// grid: (SEQ/64 q-tiles, B*H). block: 256 = 4 waves x 16 q-rows.

__global__ __launch_bounds__(256) void attn_kernel(
    const unsigned short* __restrict__ Qb, const unsigned short* __restrict__ Kb,
    const unsigned short* __restrict__ Vtb, unsigned short* __restrict__ Mg)
{
  __shared__ char Ks[64 * 128];       // [sk][d]  bf16, swizzled
  __shared__ char Vs[64 * 128];       // [d][sk]  bf16, swizzled
  __shared__ char Ps[4][16 * 128];    // per-wave P [q][sk] bf16, swizzled

  int bh = blockIdx.y;
  int q0 = blockIdx.x * 64;
  int b = bh >> 4, h = bh & 15;
  int tid = threadIdx.x, w = tid >> 6, l = tid & 63;
  int lg = l >> 4, lr = l & 15;
  const unsigned short* Qh = Qb + (size_t)bh * SEQ * HSZ;
  const unsigned short* Kh = Kb + (size_t)bh * SEQ * HSZ;
  const unsigned short* Vh = Vtb + (size_t)bh * HSZ * SEQ;

  // Q fragments in registers: lane holds Q[q0 + w*16 + lr][k2*32 + lg*8 ..+7]
  bf16x8 qf[2];
#pragma unroll
  for (int k2 = 0; k2 < 2; k2++)
    qf[k2] = *reinterpret_cast<const bf16x8*>(Qh + (size_t)(q0 + w * 16 + lr) * HSZ + k2 * 32 + lg * 8);

  f32x4 of[4];
#pragma unroll
  for (int ni = 0; ni < 4; ni++) of[ni] = (f32x4){0.f, 0.f, 0.f, 0.f};
  float m_run[4], l_run[4];
#pragma unroll
  for (int r = 0; r < 4; r++) { m_run[r] = -1e30f; l_run[r] = 0.f; }

  int srow = tid >> 3, sg = tid & 7;
  const float scale = 0.125f;   // 1/sqrt(64)

  for (int kt = 0; kt < SEQ / 64; ++kt) {
    uint4 kv0 = *reinterpret_cast<const uint4*>(Kh + (size_t)(kt * 64 + srow)      * HSZ + sg * 8);
    uint4 kv1 = *reinterpret_cast<const uint4*>(Kh + (size_t)(kt * 64 + srow + 32) * HSZ + sg * 8);
    uint4 vv0 = *reinterpret_cast<const uint4*>(Vh + (size_t)srow        * SEQ + kt * 64 + sg * 8);
    uint4 vv1 = *reinterpret_cast<const uint4*>(Vh + (size_t)(srow + 32) * SEQ + kt * 64 + sg * 8);
    __syncthreads();   // previous iter's PV reads of Vs done
    *reinterpret_cast<uint4*>(Ks + swz128(srow,      sg)) = kv0;
    *reinterpret_cast<uint4*>(Ks + swz128(srow + 32, sg)) = kv1;
    *reinterpret_cast<uint4*>(Vs + swz128(srow,      sg)) = vv0;
    *reinterpret_cast<uint4*>(Vs + swz128(srow + 32, sg)) = vv1;
    __syncthreads();

    // S = Q K^T  (per wave: 16 q-rows x 64 sk)
    f32x4 sf[4];
#pragma unroll
    for (int ni = 0; ni < 4; ni++) {
      sf[ni] = (f32x4){0.f, 0.f, 0.f, 0.f};
#pragma unroll
      for (int k2 = 0; k2 < 2; k2++) {
        bf16x8 kb = *reinterpret_cast<const bf16x8*>(Ks + swz128(ni * 16 + lr, k2 * 4 + lg));
        sf[ni] = __builtin_amdgcn_mfma_f32_16x16x32_bf16(qf[k2], kb, sf[ni], 0, 0, 0);
      }
    }

    // online softmax; lane's rows: (lg*4 + r); cols across lr (16-lane groups)
    float alpha[4];
#pragma unroll
    for (int r = 0; r < 4; r++) {
      float vm = -1e30f;
#pragma unroll
      for (int ni = 0; ni < 4; ni++) { sf[ni][r] *= scale; vm = fmaxf(vm, sf[ni][r]); }
#pragma unroll
      for (int msk = 1; msk < 16; msk <<= 1) vm = fmaxf(vm, __shfl_xor(vm, msk));
      float mn = fmaxf(m_run[r], vm);
      alpha[r] = __expf(m_run[r] - mn);
      float rs = 0.f;
#pragma unroll
      for (int ni = 0; ni < 4; ni++) {
        float p = __expf(sf[ni][r] - mn);
        sf[ni][r] = p;
        rs += p;
      }
#pragma unroll
      for (int msk = 1; msk < 16; msk <<= 1) rs += __shfl_xor(rs, msk);
      l_run[r] = l_run[r] * alpha[r] + rs;
      m_run[r] = mn;
    }

    // P -> LDS (re-layout D-frag -> A-frag), per-wave private buffer
#pragma unroll
    for (int ni = 0; ni < 4; ni++)
#pragma unroll
      for (int r = 0; r < 4; r++) {
        int prow = lg * 4 + r;
        int off = (prow << 7) + ((ni * 16 + lr) << 1);
        off ^= ((prow & 7) << 4);
        *reinterpret_cast<unsigned short*>(Ps[w] + off) = f2bf(sf[ni][r]);
      }

    // rescale O
#pragma unroll
    for (int ni = 0; ni < 4; ni++)
#pragma unroll
      for (int r = 0; r < 4; r++) of[ni][r] *= alpha[r];

    // O += P V   (contraction over sk, B-operand from Vt LDS)
#pragma unroll
    for (int k2 = 0; k2 < 2; k2++) {
      bf16x8 pa = *reinterpret_cast<const bf16x8*>(Ps[w] + swz128(lr, k2 * 4 + lg));
#pragma unroll
      for (int ni = 0; ni < 4; ni++) {
        bf16x8 vb = *reinterpret_cast<const bf16x8*>(Vs + swz128(ni * 16 + lr, k2 * 4 + lg));
        of[ni] = __builtin_amdgcn_mfma_f32_16x16x32_bf16(pa, vb, of[ni], 0, 0, 0);
      }
    }
  }

  // epilogue: merged[b][s][h*64+d] bf16
#pragma unroll
  for (int ni = 0; ni < 4; ni++)
#pragma unroll
    for (int r = 0; r < 4; r++) {
      int q = q0 + w * 16 + lg * 4 + r;
      int dm = h * 64 + ni * 16 + lr;
      float v = of[ni][r] / l_run[r];
      Mg[(size_t)(b * SEQ + q) * D_MODEL + dm] = f2bf(v);
    }
}

// ---------------- launch ----------------

extern "C" void kernel_launch(void* const* d_in, const int* in_sizes, int n_in,
                              void* d_out, int out_size, void* d_ws, size_t ws_size,
                              hipStream_t stream) {
  const float* X  = (const float*)d_in[0];
  const float* Wq = (const float*)d_in[1];
  const float* bq = (const float*)d_in[2];
  const float* Wk = (const float*)d_in[3];
  const float* bk = (const float*)d_in[4];
  const float* Wv = (const float*)d_in[5];
  const float* bv = (const float*)d_in[6];
  const float* Wo = (const float*)d_in[7];
  const float* bo = (const float*)d_in[8];
  float* out = (float*)d_out;

  char* ws = (char*)d_ws;
  unsigned short* Xbf   = (unsigned short*)(ws);                  // 8 MB (reused as merged)
  unsigned short* Wqkvt = (unsigned short*)(ws + ((size_t)8  << 20)); // 6 MB
  unsigned short* Wot   = (unsigned short*)(ws + ((size_t)14 << 20)); // 2 MB
  unsigned short* Qb    = (unsigned short*)(ws + ((size_t)16 << 20)); // 8 MB
  unsigned short* Kb    = (unsigned short*)(ws + ((size_t)24 << 20)); // 8 MB
  unsigned short* Vtb   = (unsigned short*)(ws + ((size_t)32 << 20)); // 8 MB
  unsigned short* Mg = Xbf;  // Xbf dead after QKV GEMM

  cvt_bf16_kernel<<<(TOK * D_MODEL / 4 + 255) / 256, 256, 0, stream>>>(X, Xbf, TOK * D_MODEL);
  transpose_cvt_kernel<<<dim3(32, 32, 4), dim3(32, 8), 0, stream>>>(Wq, Wk, Wv, Wo, Wqkvt, Wot);
  gemm128_kernel<0><<<dim3(24, 32), 256, 0, stream>>>(Xbf, Wqkvt, 1024, 3072,
                                                      bq, bk, bv, Qb, Kb, Vtb, nullptr);
  attn_kernel<<<dim3(SEQ / 64, BATCH * HEADS), 256, 0, stream>>>(Qb, Kb, Vtb, Mg);
  gemm128_kernel<1><<<dim3(8, 32), 256, 0, stream>>>(Mg, Wot, 1024, 1024,
                                                     bo, nullptr, nullptr,
                                                     nullptr, nullptr, nullptr, out);
}

// Round 3
// 211.297 us; speedup vs baseline: 1.2728x; 1.2728x over previous
//
#include <hip/hip_runtime.h>
#include <hip/hip_bf16.h>

#define D_MODEL 1024
#define HEADS 16
#define HSZ 64
#define BATCH 2
#define SEQ 2048
#define TOK (BATCH*SEQ)   // 4096
#define NT (SEQ/64)       // 32 k-tiles

typedef __attribute__((ext_vector_type(8))) short bf16x8;
typedef __attribute__((ext_vector_type(4))) float f32x4;

// softmax scale folded into Q at QKV epilogue: 1/sqrt(64) * log2(e)
#define QSCALE 0.1803368801111244f
// defer-max threshold in log2 domain (= 8 nats)
#define THR_L2 11.541560327f

static __device__ __forceinline__ unsigned short f2bf(float f) {
  union { float f; unsigned u; } v; v.f = f;
  unsigned r = v.u + 0x7fffu + ((v.u >> 16) & 1u);
  return (unsigned short)(r >> 16);
}

static __device__ __forceinline__ float exp2_fast(float x) {
  float r;
  asm("v_exp_f32 %0, %1" : "=v"(r) : "v"(x));
  return r;
}

static __device__ __forceinline__ unsigned cvt_pk_bf16(float a, float b) {
  unsigned r;
  asm("v_cvt_pk_bf16_f32 %0, %1, %2" : "=v"(r) : "v"(a), "v"(b));
  return r;
}

// byte-offset swizzle: row-major LDS tile with 128B rows
static __device__ __forceinline__ int swz128(int row, int g) {
  return ((row << 7) + (g << 4)) ^ ((row & 7) << 4);
}

static __device__ __forceinline__ void load_lds16(const void* g, void* l) {
  __builtin_amdgcn_global_load_lds(
      (const __attribute__((address_space(1))) unsigned*)g,
      (__attribute__((address_space(3))) unsigned*)l, 16, 0, 0);
}

// ---------------- converts ----------------

__global__ void cvt_bf16_kernel(const float* __restrict__ src,
                                unsigned short* __restrict__ dst, int n) {
  int i = (blockIdx.x * blockDim.x + threadIdx.x) * 8;
  if (i >= n) return;
  float4 v0 = *reinterpret_cast<const float4*>(src + i);
  float4 v1 = *reinterpret_cast<const float4*>(src + i + 4);
  ushort4 o0, o1;
  o0.x = f2bf(v0.x); o0.y = f2bf(v0.y); o0.z = f2bf(v0.z); o0.w = f2bf(v0.w);
  o1.x = f2bf(v1.x); o1.y = f2bf(v1.y); o1.z = f2bf(v1.z); o1.w = f2bf(v1.w);
  *reinterpret_cast<ushort4*>(dst + i) = o0;
  *reinterpret_cast<ushort4*>(dst + i + 4) = o1;
}

// W[i][o] fp32 -> Wt[o][i] bf16. z = 0..2: Wq/Wk/Wv into Wqkvt; z = 3: Wo.
__global__ void transpose_cvt_kernel(const float* __restrict__ Wq, const float* __restrict__ Wk,
                                     const float* __restrict__ Wv, const float* __restrict__ Wo,
                                     unsigned short* __restrict__ Wqkvt,
                                     unsigned short* __restrict__ Wot) {
  __shared__ float tile[32][33];
  int m = blockIdx.z;
  const float* src = (m == 0) ? Wq : (m == 1) ? Wk : (m == 2) ? Wv : Wo;
  unsigned short* dst = (m < 3) ? (Wqkvt + (size_t)m * D_MODEL * D_MODEL) : Wot;
  int i0 = blockIdx.y * 32, o0 = blockIdx.x * 32;
  int tx = threadIdx.x, ty = threadIdx.y;
  for (int k = 0; k < 32; k += 8)
    tile[ty + k][tx] = src[(size_t)(i0 + ty + k) * D_MODEL + o0 + tx];
  __syncthreads();
  for (int k = 0; k < 32; k += 8)
    dst[(size_t)(o0 + ty + k) * D_MODEL + i0 + tx] = f2bf(tile[tx][ty + k]);
}

// ---------------- 128x128 bf16 GEMM (m97 structure: global_load_lds, linear LDS)
// C = A[M,K] @ Bt[N,K]^T.  EPI 0: QKV epilogue (bias + Q-prescale + scatter).
// EPI 1: fp32 out + bias.

template<int EPI>
__global__ __launch_bounds__(256) void gemm128_kernel(
    const unsigned short* __restrict__ A, const unsigned short* __restrict__ Bt,
    int K, int N,
    const float* __restrict__ b0, const float* __restrict__ b1, const float* __restrict__ b2,
    unsigned short* __restrict__ Qb, unsigned short* __restrict__ Kb,
    unsigned short* __restrict__ Vtb, float* __restrict__ Cout)
{
  __shared__ char As[128 * 64];   // 128 rows x 32 bf16, LINEAR (gload_lds dest)
  __shared__ char Bs[128 * 64];
  int m0 = blockIdx.y * 128, n0 = blockIdx.x * 128;
  int tid = threadIdx.x;
  int wv = tid >> 6, l = tid & 63;
  int wm = wv >> 1, wn = wv & 1;
  int lg = l >> 4, lr = l & 15;
  int srow = wv * 32 + (l >> 2);      // staging row (this lane's global row)
  int scol = (l & 3) * 8;             // staging k-offset (elements)

  f32x4 acc[4][4];
#pragma unroll
  for (int i = 0; i < 4; i++)
#pragma unroll
    for (int j = 0; j < 4; j++) acc[i][j] = (f32x4){0.f, 0.f, 0.f, 0.f};

  for (int k0 = 0; k0 < K; k0 += 32) {
    __syncthreads();   // previous iter's fragment reads done
    const unsigned short* ga = A  + (size_t)(m0 + srow) * K + k0 + scol;
    const unsigned short* gb = Bt + (size_t)(n0 + srow) * K + k0 + scol;
    load_lds16(ga,                       As + wv * 2048);
    load_lds16(ga + (size_t)16 * K,      As + wv * 2048 + 1024);
    load_lds16(gb,                       Bs + wv * 2048);
    load_lds16(gb + (size_t)16 * K,      Bs + wv * 2048 + 1024);
    __syncthreads();   // compiler drains vmcnt before barrier -> LDS visible

    bf16x8 af[4], bfv[4];
#pragma unroll
    for (int mi = 0; mi < 4; mi++)
      af[mi] = *reinterpret_cast<const bf16x8*>(As + (wm * 64 + mi * 16 + lr) * 64 + lg * 16);
#pragma unroll
    for (int ni = 0; ni < 4; ni++)
      bfv[ni] = *reinterpret_cast<const bf16x8*>(Bs + (wn * 64 + ni * 16 + lr) * 64 + lg * 16);
#pragma unroll
    for (int mi = 0; mi < 4; mi++)
#pragma unroll
      for (int ni = 0; ni < 4; ni++)
        acc[mi][ni] = __builtin_amdgcn_mfma_f32_16x16x32_bf16(af[mi], bfv[ni], acc[mi][ni], 0, 0, 0);
  }

  // epilogue: D frag mapping col = lane&15, row = (lane>>4)*4 + r
#pragma unroll
  for (int mi = 0; mi < 4; mi++) {
    int gr0 = m0 + wm * 64 + mi * 16 + lg * 4;
#pragma unroll
    for (int ni = 0; ni < 4; ni++) {
      int gc = n0 + wn * 64 + ni * 16 + lr;
      if (EPI == 0) {
        int mat = gc >> 10, o = gc & 1023;
        int hh = o >> 6, d = o & 63;
        const float* bias = (mat == 0) ? b0 : (mat == 1) ? b1 : b2;
        float bv = bias[o];
#pragma unroll
        for (int r = 0; r < 4; r++) {
          int t = gr0 + r;
          int b = t >> 11, s = t & 2047;
          float v = acc[mi][ni][r] + bv;
          if (mat == 0) v *= QSCALE;          // fold softmax scale * log2e into Q
          unsigned short u = f2bf(v);
          size_t head = (size_t)(b * HEADS + hh);
          if (mat == 0)      Qb [(head * SEQ + s) * HSZ + d] = u;
          else if (mat == 1) Kb [(head * SEQ + s) * HSZ + d] = u;
          else               Vtb[(head * HSZ + d) * SEQ + s] = u;   // V transposed
        }
      } else {
        float bv = b0[gc];
#pragma unroll
        for (int r = 0; r < 4; r++) {
          int t = gr0 + r;
          Cout[(size_t)t * N + gc] = acc[mi][ni][r] + bv;
        }
      }
    }
  }
}

// ---------------- flash attention ----------------
// grid: (SEQ/128 q-tiles, B*H) XCD-swizzled. block: 256 = 4 waves x 32 q-rows.
// Swapped QK^T: S = mfma(K, Q) puts q in D-columns -> k-axis (softmax reduce)
// is mostly lane-local. l computed by ones-column MFMA. exp2 domain (Q prescaled).

__global__ __launch_bounds__(256, 2) void attn_kernel(
    const unsigned short* __restrict__ Qb, const unsigned short* __restrict__ Kb,
    const unsigned short* __restrict__ Vtb, unsigned short* __restrict__ Mg)
{
  __shared__ char Ks[64 * 128];       // [sk][d]  bf16, swizzled
  __shared__ char Vs[64 * 128];       // [d][sk]  bf16, swizzled
  __shared__ char Ps[4][32 * 128];    // per-wave P [q][sk] bf16, swizzled

  // XCD-chunked swizzle: 512 blocks -> 64 consecutive per XCD -> 4 heads/XCD (K/V L2-resident)
  int orig = blockIdx.y * 16 + blockIdx.x;
  int swzb = (orig & 7) * 64 + (orig >> 3);
  int bh = swzb >> 4;
  int q0 = (swzb & 15) * 128;
  int b = bh >> 4, h = bh & 15;
  int tid = threadIdx.x, w = tid >> 6, l = tid & 63;
  int lg = l >> 4, lr = l & 15;
  const unsigned short* Qh = Qb + (size_t)bh * SEQ * HSZ;
  const unsigned short* Kh = Kb + (size_t)bh * SEQ * HSZ;
  const unsigned short* Vh = Vtb + (size_t)bh * HSZ * SEQ;

  // Q as MFMA B-fragments: lane holds Q[q0+w*32+qf*16+lr][k2*32+lg*8 ..+7] (prescaled)
  bf16x8 qfr[2][2];
#pragma unroll
  for (int qf = 0; qf < 2; qf++)
#pragma unroll
    for (int k2 = 0; k2 < 2; k2++)
      qfr[qf][k2] = *reinterpret_cast<const bf16x8*>(
          Qh + (size_t)(q0 + w * 32 + qf * 16 + lr) * HSZ + k2 * 32 + lg * 8);

  f32x4 of[2][4];       // O accum: [qfrag][d-frag]
  f32x4 lones[2];       // row-sum accum via ones-MFMA
#pragma unroll
  for (int qf = 0; qf < 2; qf++) {
    lones[qf] = (f32x4){0.f, 0.f, 0.f, 0.f};
#pragma unroll
    for (int ni = 0; ni < 4; ni++) of[qf][ni] = (f32x4){0.f, 0.f, 0.f, 0.f};
  }
  float m0r = -1e30f, m1r = -1e30f;   // running max (log2 domain), per q-col frag

  bf16x8 vone;
#pragma unroll
  for (int j = 0; j < 8; j++) vone[j] = (short)0x3F80;   // bf16 1.0

  int srow = tid >> 3, sg = tid & 7;

  // prologue: tile 0 loads
  uint4 ka  = *reinterpret_cast<const uint4*>(Kh + (size_t)srow * HSZ + sg * 8);
  uint4 kb2 = *reinterpret_cast<const uint4*>(Kh + (size_t)(srow + 32) * HSZ + sg * 8);
  uint4 va  = *reinterpret_cast<const uint4*>(Vh + (size_t)srow * SEQ + sg * 8);
  uint4 vb2 = *reinterpret_cast<const uint4*>(Vh + (size_t)(srow + 32) * SEQ + sg * 8);

  for (int kt = 0; kt < NT; ++kt) {
    __syncthreads();   // prev tile's K/V LDS reads done
    *reinterpret_cast<uint4*>(Ks + swz128(srow,      sg)) = ka;
    *reinterpret_cast<uint4*>(Ks + swz128(srow + 32, sg)) = kb2;
    *reinterpret_cast<uint4*>(Vs + swz128(srow,      sg)) = va;
    *reinterpret_cast<uint4*>(Vs + swz128(srow + 32, sg)) = vb2;
    __syncthreads();

    // T14: issue next tile's loads now; they fly under this tile's compute
    if (kt + 1 < NT) {
      const unsigned short* Kn = Kh + (size_t)(kt + 1) * 64 * HSZ;
      const unsigned short* Vn = Vh + (kt + 1) * 64;
      ka  = *reinterpret_cast<const uint4*>(Kn + (size_t)srow * HSZ + sg * 8);
      kb2 = *reinterpret_cast<const uint4*>(Kn + (size_t)(srow + 32) * HSZ + sg * 8);
      va  = *reinterpret_cast<const uint4*>(Vn + (size_t)srow * SEQ + sg * 8);
      vb2 = *reinterpret_cast<const uint4*>(Vn + (size_t)(srow + 32) * SEQ + sg * 8);
    }

    // S = K Q (swapped): S[k = ni*16+lg*4+r][q = qf*16+lr]
    bf16x8 kf[4][2];
#pragma unroll
    for (int ni = 0; ni < 4; ni++)
#pragma unroll
      for (int k2 = 0; k2 < 2; k2++)
        kf[ni][k2] = *reinterpret_cast<const bf16x8*>(Ks + swz128(ni * 16 + lr, k2 * 4 + lg));

    f32x4 sf[2][4];
#pragma unroll
    for (int qf = 0; qf < 2; qf++)
#pragma unroll
      for (int ni = 0; ni < 4; ni++) {
        sf[qf][ni] = (f32x4){0.f, 0.f, 0.f, 0.f};
#pragma unroll
        for (int k2 = 0; k2 < 2; k2++)
          sf[qf][ni] = __builtin_amdgcn_mfma_f32_16x16x32_bf16(kf[ni][k2], qfr[qf][k2], sf[qf][ni], 0, 0, 0);
      }

    // local max over the 16 in-lane k-values per q-col (clang fuses to v_max3)
    float lm0 = fmaxf(fmaxf(fmaxf(sf[0][0][0], sf[0][0][1]), fmaxf(sf[0][0][2], sf[0][0][3])),
                      fmaxf(fmaxf(sf[0][1][0], sf[0][1][1]), fmaxf(sf[0][1][2], sf[0][1][3])));
    lm0 = fmaxf(lm0,
          fmaxf(fmaxf(fmaxf(sf[0][2][0], sf[0][2][1]), fmaxf(sf[0][2][2], sf[0][2][3])),
                fmaxf(fmaxf(sf[0][3][0], sf[0][3][1]), fmaxf(sf[0][3][2], sf[0][3][3]))));
    float lm1 = fmaxf(fmaxf(fmaxf(sf[1][0][0], sf[1][0][1]), fmaxf(sf[1][0][2], sf[1][0][3])),
                      fmaxf(fmaxf(sf[1][1][0], sf[1][1][1]), fmaxf(sf[1][1][2], sf[1][1][3])));
    lm1 = fmaxf(lm1,
          fmaxf(fmaxf(fmaxf(sf[1][2][0], sf[1][2][1]), fmaxf(sf[1][2][2], sf[1][2][3])),
                fmaxf(fmaxf(sf[1][3][0], sf[1][3][1]), fmaxf(sf[1][3][2], sf[1][3][3]))));

    // defer-max: only do the full reduce + rescale when some row grew past THR
    int grow = (lm0 > m0r + THR_L2) || (lm1 > m1r + THR_L2);
    if (__any(grow)) {
      float vm0 = fmaxf(lm0, __shfl_xor(lm0, 16));
      vm0 = fmaxf(vm0, __shfl_xor(vm0, 32));
      float vm1 = fmaxf(lm1, __shfl_xor(lm1, 16));
      vm1 = fmaxf(vm1, __shfl_xor(vm1, 32));
      float mn0 = fmaxf(m0r, vm0), mn1 = fmaxf(m1r, vm1);
      float al0 = exp2_fast(m0r - mn0), al1 = exp2_fast(m1r - mn1);
      m0r = mn0; m1r = mn1;
      // O/l rows are q = qf*16 + lg*4 + r; alpha lives at lane lr = q&15
#pragma unroll
      for (int r = 0; r < 4; r++) {
        float a0 = __shfl(al0, lg * 4 + r, 16);
        float a1 = __shfl(al1, lg * 4 + r, 16);
        lones[0][r] *= a0; lones[1][r] *= a1;
#pragma unroll
        for (int ni = 0; ni < 4; ni++) { of[0][ni][r] *= a0; of[1][ni][r] *= a1; }
      }
    }

    // P = exp2(S - m); pack pairs; write per-wave P tile (b64, swizzled)
#pragma unroll
    for (int qf = 0; qf < 2; qf++) {
      float mq = qf ? m1r : m0r;
      int prow = qf * 16 + lr;
#pragma unroll
      for (int ni = 0; ni < 4; ni++) {
        float p0 = exp2_fast(sf[qf][ni][0] - mq);
        float p1 = exp2_fast(sf[qf][ni][1] - mq);
        float p2 = exp2_fast(sf[qf][ni][2] - mq);
        float p3 = exp2_fast(sf[qf][ni][3] - mq);
        uint2 pw;
        pw.x = cvt_pk_bf16(p0, p1);
        pw.y = cvt_pk_bf16(p2, p3);
        int off = ((prow << 7) + (ni << 5) + (lg << 3)) ^ ((prow & 7) << 4);
        *reinterpret_cast<uint2*>(Ps[w] + off) = pw;
      }
    }

    // O += P V ; l += P 1   (per-wave Ps: no barrier, compiler waits lgkmcnt)
    bf16x8 vf[4][2];
#pragma unroll
    for (int ni = 0; ni < 4; ni++)
#pragma unroll
      for (int k2 = 0; k2 < 2; k2++)
        vf[ni][k2] = *reinterpret_cast<const bf16x8*>(Vs + swz128(ni * 16 + lr, k2 * 4 + lg));
    bf16x8 pa[2][2];
#pragma unroll
    for (int qf = 0; qf < 2; qf++)
#pragma unroll
      for (int k2 = 0; k2 < 2; k2++)
        pa[qf][k2] = *reinterpret_cast<const bf16x8*>(Ps[w] + swz128(qf * 16 + lr, k2 * 4 + lg));
#pragma unroll
    for (int qf = 0; qf < 2; qf++) {
#pragma unroll
      for (int k2 = 0; k2 < 2; k2++)
        lones[qf] = __builtin_amdgcn_mfma_f32_16x16x32_bf16(pa[qf][k2], vone, lones[qf], 0, 0, 0);
#pragma unroll
      for (int ni = 0; ni < 4; ni++)
#pragma unroll
        for (int k2 = 0; k2 < 2; k2++)
          of[qf][ni] = __builtin_amdgcn_mfma_f32_16x16x32_bf16(pa[qf][k2], vf[ni][k2], of[qf][ni], 0, 0, 0);
    }
  }

  // epilogue: merged[b][q][h*64+d], O row q = q0+w*32+qf*16+lg*4+r, col d = ni*16+lr
#pragma unroll
  for (int qf = 0; qf < 2; qf++)
#pragma unroll
    for (int r = 0; r < 4; r++) {
      float inv = 1.0f / lones[qf][r];
      int q = q0 + w * 32 + qf * 16 + lg * 4 + r;
#pragma unroll
      for (int ni = 0; ni < 4; ni++) {
        int dm = h * 64 + ni * 16 + lr;
        Mg[(size_t)(b * SEQ + q) * D_MODEL + dm] = f2bf(of[qf][ni][r] * inv);
      }
    }
}

// ---------------- launch ----------------

extern "C" void kernel_launch(void* const* d_in, const int* in_sizes, int n_in,
                              void* d_out, int out_size, void* d_ws, size_t ws_size,
                              hipStream_t stream) {
  const float* X  = (const float*)d_in[0];
  const float* Wq = (const float*)d_in[1];
  const float* bq = (const float*)d_in[2];
  const float* Wk = (const float*)d_in[3];
  const float* bk = (const float*)d_in[4];
  const float* Wv = (const float*)d_in[5];
  const float* bv = (const float*)d_in[6];
  const float* Wo = (const float*)d_in[7];
  const float* bo = (const float*)d_in[8];
  float* out = (float*)d_out;

  char* ws = (char*)d_ws;
  unsigned short* Xbf   = (unsigned short*)(ws);                      // 8 MB (reused as merged)
  unsigned short* Wqkvt = (unsigned short*)(ws + ((size_t)8  << 20)); // 6 MB
  unsigned short* Wot   = (unsigned short*)(ws + ((size_t)14 << 20)); // 2 MB
  unsigned short* Qb    = (unsigned short*)(ws + ((size_t)16 << 20)); // 8 MB
  unsigned short* Kb    = (unsigned short*)(ws + ((size_t)24 << 20)); // 8 MB
  unsigned short* Vtb   = (unsigned short*)(ws + ((size_t)32 << 20)); // 8 MB
  unsigned short* Mg = Xbf;  // Xbf dead after QKV GEMM

  cvt_bf16_kernel<<<(TOK * D_MODEL / 8 + 255) / 256, 256, 0, stream>>>(X, Xbf, TOK * D_MODEL);
  transpose_cvt_kernel<<<dim3(32, 32, 4), dim3(32, 8), 0, stream>>>(Wq, Wk, Wv, Wo, Wqkvt, Wot);
  gemm128_kernel<0><<<dim3(24, 32), 256, 0, stream>>>(Xbf, Wqkvt, 1024, 3072,
                                                      bq, bk, bv, Qb, Kb, Vtb, nullptr);
  attn_kernel<<<dim3(16, 32), 256, 0, stream>>>(Qb, Kb, Vtb, Mg);
  gemm128_kernel<1><<<dim3(8, 32), 256, 0, stream>>>(Mg, Wot, 1024, 1024,
                                                     bo, nullptr, nullptr,
                                                     nullptr, nullptr, nullptr, out);
}

// Round 4
// 209.043 us; speedup vs baseline: 1.2865x; 1.0108x over previous
//
#include <hip/hip_runtime.h>
#include <hip/hip_bf16.h>

#define D_MODEL 1024
#define HEADS 16
#define HSZ 64
#define BATCH 2
#define SEQ 2048
#define TOK (BATCH*SEQ)   // 4096
#define NT (SEQ/64)       // 32 k-tiles

typedef __attribute__((ext_vector_type(8))) short bf16x8;
typedef __attribute__((ext_vector_type(4))) float f32x4;

// softmax scale folded into Q at QKV epilogue: 1/sqrt(64) * log2(e)
#define QSCALE 0.1803368801111244f
// defer-max threshold in log2 domain (= 8 nats)
#define THR_L2 11.541560327f

static __device__ __forceinline__ unsigned short f2bf(float f) {
  union { float f; unsigned u; } v; v.f = f;
  unsigned r = v.u + 0x7fffu + ((v.u >> 16) & 1u);
  return (unsigned short)(r >> 16);
}

static __device__ __forceinline__ float exp2_fast(float x) {
  float r;
  asm("v_exp_f32 %0, %1" : "=v"(r) : "v"(x));
  return r;
}

static __device__ __forceinline__ unsigned cvt_pk_bf16(float a, float b) {
  unsigned r;
  asm("v_cvt_pk_bf16_f32 %0, %1, %2" : "=v"(r) : "v"(a), "v"(b));
  return r;
}

// byte-offset swizzle: row-major LDS tile with 128B rows (16B granular XOR)
static __device__ __forceinline__ int swz128(int row, int g) {
  return ((row << 7) + (g << 4)) ^ ((row & 7) << 4);
}

// P-tile slot swizzle: 16 8B-slots per 128B row; xs bijective over 16 lanes
static __device__ __forceinline__ int xs4(int lr) {
  return ((lr & 7) << 1) | (lr >> 3);
}

static __device__ __forceinline__ void load_lds16(const void* g, void* l) {
  __builtin_amdgcn_global_load_lds(
      (const __attribute__((address_space(1))) unsigned*)g,
      (__attribute__((address_space(3))) unsigned*)l, 16, 0, 0);
}

// ---------------- converts ----------------

__global__ void cvt_bf16_kernel(const float* __restrict__ src,
                                unsigned short* __restrict__ dst, int n) {
  int i = (blockIdx.x * blockDim.x + threadIdx.x) * 8;
  if (i >= n) return;
  float4 v0 = *reinterpret_cast<const float4*>(src + i);
  float4 v1 = *reinterpret_cast<const float4*>(src + i + 4);
  ushort4 o0, o1;
  o0.x = f2bf(v0.x); o0.y = f2bf(v0.y); o0.z = f2bf(v0.z); o0.w = f2bf(v0.w);
  o1.x = f2bf(v1.x); o1.y = f2bf(v1.y); o1.z = f2bf(v1.z); o1.w = f2bf(v1.w);
  *reinterpret_cast<ushort4*>(dst + i) = o0;
  *reinterpret_cast<ushort4*>(dst + i + 4) = o1;
}

// W[i][o] fp32 -> Wt[o][i] bf16. z = 0..2: Wq/Wk/Wv into Wqkvt; z = 3: Wo.
__global__ void transpose_cvt_kernel(const float* __restrict__ Wq, const float* __restrict__ Wk,
                                     const float* __restrict__ Wv, const float* __restrict__ Wo,
                                     unsigned short* __restrict__ Wqkvt,
                                     unsigned short* __restrict__ Wot) {
  __shared__ float tile[32][33];
  int m = blockIdx.z;
  const float* src = (m == 0) ? Wq : (m == 1) ? Wk : (m == 2) ? Wv : Wo;
  unsigned short* dst = (m < 3) ? (Wqkvt + (size_t)m * D_MODEL * D_MODEL) : Wot;
  int i0 = blockIdx.y * 32, o0 = blockIdx.x * 32;
  int tx = threadIdx.x, ty = threadIdx.y;
  for (int k = 0; k < 32; k += 8)
    tile[ty + k][tx] = src[(size_t)(i0 + ty + k) * D_MODEL + o0 + tx];
  __syncthreads();
  for (int k = 0; k < 32; k += 8)
    dst[(size_t)(o0 + ty + k) * D_MODEL + i0 + tx] = f2bf(tile[tx][ty + k]);
}

// ---------------- 128x128 bf16 GEMM (m97 structure: global_load_lds, linear LDS)
// C = A[M,K] @ Bt[N,K]^T.  EPI 0: QKV epilogue (bias + Q-prescale + scatter).
// EPI 1: fp32 out + bias.

template<int EPI>
__global__ __launch_bounds__(256) void gemm128_kernel(
    const unsigned short* __restrict__ A, const unsigned short* __restrict__ Bt,
    int K, int N,
    const float* __restrict__ b0, const float* __restrict__ b1, const float* __restrict__ b2,
    unsigned short* __restrict__ Qb, unsigned short* __restrict__ Kb,
    unsigned short* __restrict__ Vtb, float* __restrict__ Cout)
{
  __shared__ char As[128 * 64];   // 128 rows x 32 bf16, LINEAR (gload_lds dest)
  __shared__ char Bs[128 * 64];
  int m0 = blockIdx.y * 128, n0 = blockIdx.x * 128;
  int tid = threadIdx.x;
  int wv = tid >> 6, l = tid & 63;
  int wm = wv >> 1, wn = wv & 1;
  int lg = l >> 4, lr = l & 15;
  int srow = wv * 32 + (l >> 2);      // staging row (this lane's global row)
  int scol = (l & 3) * 8;             // staging k-offset (elements)

  f32x4 acc[4][4];
#pragma unroll
  for (int i = 0; i < 4; i++)
#pragma unroll
    for (int j = 0; j < 4; j++) acc[i][j] = (f32x4){0.f, 0.f, 0.f, 0.f};

  for (int k0 = 0; k0 < K; k0 += 32) {
    __syncthreads();   // previous iter's fragment reads done
    const unsigned short* ga = A  + (size_t)(m0 + srow) * K + k0 + scol;
    const unsigned short* gb = Bt + (size_t)(n0 + srow) * K + k0 + scol;
    load_lds16(ga,                       As + wv * 2048);
    load_lds16(ga + (size_t)16 * K,      As + wv * 2048 + 1024);
    load_lds16(gb,                       Bs + wv * 2048);
    load_lds16(gb + (size_t)16 * K,      Bs + wv * 2048 + 1024);
    __syncthreads();   // compiler drains vmcnt before barrier -> LDS visible

    bf16x8 af[4], bfv[4];
#pragma unroll
    for (int mi = 0; mi < 4; mi++)
      af[mi] = *reinterpret_cast<const bf16x8*>(As + (wm * 64 + mi * 16 + lr) * 64 + lg * 16);
#pragma unroll
    for (int ni = 0; ni < 4; ni++)
      bfv[ni] = *reinterpret_cast<const bf16x8*>(Bs + (wn * 64 + ni * 16 + lr) * 64 + lg * 16);
#pragma unroll
    for (int mi = 0; mi < 4; mi++)
#pragma unroll
      for (int ni = 0; ni < 4; ni++)
        acc[mi][ni] = __builtin_amdgcn_mfma_f32_16x16x32_bf16(af[mi], bfv[ni], acc[mi][ni], 0, 0, 0);
  }

  // epilogue: D frag mapping col = lane&15, row = (lane>>4)*4 + r
#pragma unroll
  for (int mi = 0; mi < 4; mi++) {
    int gr0 = m0 + wm * 64 + mi * 16 + lg * 4;
#pragma unroll
    for (int ni = 0; ni < 4; ni++) {
      int gc = n0 + wn * 64 + ni * 16 + lr;
      if (EPI == 0) {
        int mat = gc >> 10, o = gc & 1023;
        int hh = o >> 6, d = o & 63;
        const float* bias = (mat == 0) ? b0 : (mat == 1) ? b1 : b2;
        float bv = bias[o];
#pragma unroll
        for (int r = 0; r < 4; r++) {
          int t = gr0 + r;
          int b = t >> 11, s = t & 2047;
          float v = acc[mi][ni][r] + bv;
          if (mat == 0) v *= QSCALE;          // fold softmax scale * log2e into Q
          unsigned short u = f2bf(v);
          size_t head = (size_t)(b * HEADS + hh);
          if (mat == 0)      Qb [(head * SEQ + s) * HSZ + d] = u;
          else if (mat == 1) Kb [(head * SEQ + s) * HSZ + d] = u;
          else               Vtb[(head * HSZ + d) * SEQ + s] = u;   // V transposed
        }
      } else {
        float bv = b0[gc];
#pragma unroll
        for (int r = 0; r < 4; r++) {
          int t = gr0 + r;
          Cout[(size_t)t * N + gc] = acc[mi][ni][r] + bv;
        }
      }
    }
  }
}

// ---------------- flash attention ----------------
// grid: (SEQ/128 q-tiles, B*H) XCD-swizzled. block: 512 = 8 waves x 16 q-rows.
// Swapped QK^T: S = mfma(K, Q); k-axis softmax reduce mostly lane-local.
// l via ones-MFMA; exp2 domain (Q prescaled by 1/sqrt(d)*log2e at QKV epilogue).

__global__ __launch_bounds__(512, 4) void attn_kernel(
    const unsigned short* __restrict__ Qb, const unsigned short* __restrict__ Kb,
    const unsigned short* __restrict__ Vtb, unsigned short* __restrict__ Mg)
{
  __shared__ char Ks[64 * 128];       // [sk][d]  bf16, swizzled (swz128)
  __shared__ char Vs[64 * 128];       // [d][sk]  bf16, swizzled (swz128)
  __shared__ char Ps[8][16 * 128];    // per-wave P [q][sk] bf16, slot-swizzled

  // XCD-chunked swizzle: 512 blocks -> 64 consecutive per XCD -> 4 heads/XCD
  int orig = blockIdx.y * 16 + blockIdx.x;
  int swzb = (orig & 7) * 64 + (orig >> 3);
  int bh = swzb >> 4;
  int q0 = (swzb & 15) * 128;
  int b = bh >> 4, h = bh & 15;
  int tid = threadIdx.x, w = tid >> 6, l = tid & 63;
  int lg = l >> 4, lr = l & 15;
  const unsigned short* Qh = Qb + (size_t)bh * SEQ * HSZ;
  const unsigned short* Kh = Kb + (size_t)bh * SEQ * HSZ;
  const unsigned short* Vh = Vtb + (size_t)bh * HSZ * SEQ;

  // Q as MFMA B-fragments: lane holds Q[q0+w*16+lr][k2*32+lg*8 ..+7] (prescaled)
  bf16x8 qf2[2];
#pragma unroll
  for (int k2 = 0; k2 < 2; k2++)
    qf2[k2] = *reinterpret_cast<const bf16x8*>(
        Qh + (size_t)(q0 + w * 16 + lr) * HSZ + k2 * 32 + lg * 8);

  f32x4 of[4];          // O accum per d-frag; rows q = lg*4+r
  f32x4 lones;          // row-sum accum via ones-MFMA
#pragma unroll
  for (int ni = 0; ni < 4; ni++) of[ni] = (f32x4){0.f, 0.f, 0.f, 0.f};
  lones = (f32x4){0.f, 0.f, 0.f, 0.f};
  float m_r = -1e30f;   // running max (log2 domain); valid at lane lr = q&15

  bf16x8 vone;
#pragma unroll
  for (int j = 0; j < 8; j++) vone[j] = (short)0x3F80;   // bf16 1.0

  int srow = tid >> 3, sg = tid & 7;   // 512 threads cover 64 rows x 8 slots

  // prologue: tile 0 loads (one K row-chunk + one V row-chunk per thread)
  uint4 ka = *reinterpret_cast<const uint4*>(Kh + (size_t)srow * HSZ + sg * 8);
  uint4 va = *reinterpret_cast<const uint4*>(Vh + (size_t)srow * SEQ + sg * 8);

  for (int kt = 0; kt < NT; ++kt) {
    __syncthreads();   // prev tile's K/V LDS reads done
    *reinterpret_cast<uint4*>(Ks + swz128(srow, sg)) = ka;
    *reinterpret_cast<uint4*>(Vs + swz128(srow, sg)) = va;
    __syncthreads();

    // T14: issue next tile's loads now; they fly under this tile's compute
    if (kt + 1 < NT) {
      ka = *reinterpret_cast<const uint4*>(Kh + (size_t)((kt + 1) * 64 + srow) * HSZ + sg * 8);
      va = *reinterpret_cast<const uint4*>(Vh + (size_t)srow * SEQ + (kt + 1) * 64 + sg * 8);
    }

    // S = K Q (swapped): lane holds S[sk = ni*16+lg*4+r][q = lr]
    f32x4 sf[4];
#pragma unroll
    for (int ni = 0; ni < 4; ni++) {
      sf[ni] = (f32x4){0.f, 0.f, 0.f, 0.f};
#pragma unroll
      for (int k2 = 0; k2 < 2; k2++) {
        bf16x8 kf = *reinterpret_cast<const bf16x8*>(Ks + swz128(ni * 16 + lr, k2 * 4 + lg));
        sf[ni] = __builtin_amdgcn_mfma_f32_16x16x32_bf16(kf, qf2[k2], sf[ni], 0, 0, 0);
      }
    }

    // local max over the 16 in-lane k-values for q-col lr
    float lm = fmaxf(fmaxf(fmaxf(sf[0][0], sf[0][1]), fmaxf(sf[0][2], sf[0][3])),
                     fmaxf(fmaxf(sf[1][0], sf[1][1]), fmaxf(sf[1][2], sf[1][3])));
    lm = fmaxf(lm,
         fmaxf(fmaxf(fmaxf(sf[2][0], sf[2][1]), fmaxf(sf[2][2], sf[2][3])),
               fmaxf(fmaxf(sf[3][0], sf[3][1]), fmaxf(sf[3][2], sf[3][3]))));

    // defer-max: full reduce + rescale only when a row grew past THR
    if (__any(lm > m_r + THR_L2)) {
      float vm = fmaxf(lm, __shfl_xor(lm, 16));
      vm = fmaxf(vm, __shfl_xor(vm, 32));
      float mn = fmaxf(m_r, vm);
      float al = exp2_fast(m_r - mn);
      m_r = mn;
      // O/l rows are q = lg*4 + r; alpha lives at lane lr = q&15
#pragma unroll
      for (int r = 0; r < 4; r++) {
        float a = __shfl(al, lg * 4 + r, 16);
        lones[r] *= a;
#pragma unroll
        for (int ni = 0; ni < 4; ni++) of[ni][r] *= a;
      }
    }

    // P = exp2(S - m); pack pairs; write per-wave P tile.
    // Slot layout: row q=lr, 16 8B-slots; slot for sk-group g = g ^ xs4(lr).
#pragma unroll
    for (int ni = 0; ni < 4; ni++) {
      float p0 = exp2_fast(sf[ni][0] - m_r);
      float p1 = exp2_fast(sf[ni][1] - m_r);
      float p2 = exp2_fast(sf[ni][2] - m_r);
      float p3 = exp2_fast(sf[ni][3] - m_r);
      uint2 pw;
      pw.x = cvt_pk_bf16(p0, p1);
      pw.y = cvt_pk_bf16(p2, p3);
      int slot = (ni * 4 + lg) ^ xs4(lr);
      *reinterpret_cast<uint2*>(Ps[w] + (lr << 7) + (slot << 3)) = pw;
    }

    // assemble PV A-fragments: lane needs P[q=lr][sk = k2*32 + lg*8 + j]
    bf16x8 pa[2];
#pragma unroll
    for (int k2 = 0; k2 < 2; k2++) {
      int g0 = k2 * 8 + lg * 2;
      uint2 lo = *reinterpret_cast<const uint2*>(Ps[w] + (lr << 7) + (((g0)     ^ xs4(lr)) << 3));
      uint2 hi = *reinterpret_cast<const uint2*>(Ps[w] + (lr << 7) + (((g0 + 1) ^ xs4(lr)) << 3));
      int4 t = {(int)lo.x, (int)lo.y, (int)hi.x, (int)hi.y};
      pa[k2] = *reinterpret_cast<bf16x8*>(&t);
    }

    // O += P V ; l += P 1
    __builtin_amdgcn_s_setprio(1);
#pragma unroll
    for (int k2 = 0; k2 < 2; k2++)
      lones = __builtin_amdgcn_mfma_f32_16x16x32_bf16(pa[k2], vone, lones, 0, 0, 0);
#pragma unroll
    for (int ni = 0; ni < 4; ni++)
#pragma unroll
      for (int k2 = 0; k2 < 2; k2++) {
        bf16x8 vf = *reinterpret_cast<const bf16x8*>(Vs + swz128(ni * 16 + lr, k2 * 4 + lg));
        of[ni] = __builtin_amdgcn_mfma_f32_16x16x32_bf16(pa[k2], vf, of[ni], 0, 0, 0);
      }
    __builtin_amdgcn_s_setprio(0);
  }

  // epilogue: merged[b][q][h*64+d], q = q0+w*16+lg*4+r, d = ni*16+lr
#pragma unroll
  for (int r = 0; r < 4; r++) {
    float inv = 1.0f / lones[r];
    int q = q0 + w * 16 + lg * 4 + r;
#pragma unroll
    for (int ni = 0; ni < 4; ni++) {
      int dm = h * 64 + ni * 16 + lr;
      Mg[(size_t)(b * SEQ + q) * D_MODEL + dm] = f2bf(of[ni][r] * inv);
    }
  }
}

// ---------------- launch ----------------

extern "C" void kernel_launch(void* const* d_in, const int* in_sizes, int n_in,
                              void* d_out, int out_size, void* d_ws, size_t ws_size,
                              hipStream_t stream) {
  const float* X  = (const float*)d_in[0];
  const float* Wq = (const float*)d_in[1];
  const float* bq = (const float*)d_in[2];
  const float* Wk = (const float*)d_in[3];
  const float* bk = (const float*)d_in[4];
  const float* Wv = (const float*)d_in[5];
  const float* bv = (const float*)d_in[6];
  const float* Wo = (const float*)d_in[7];
  const float* bo = (const float*)d_in[8];
  float* out = (float*)d_out;

  char* ws = (char*)d_ws;
  unsigned short* Xbf   = (unsigned short*)(ws);                      // 8 MB (reused as merged)
  unsigned short* Wqkvt = (unsigned short*)(ws + ((size_t)8  << 20)); // 6 MB
  unsigned short* Wot   = (unsigned short*)(ws + ((size_t)14 << 20)); // 2 MB
  unsigned short* Qb    = (unsigned short*)(ws + ((size_t)16 << 20)); // 8 MB
  unsigned short* Kb    = (unsigned short*)(ws + ((size_t)24 << 20)); // 8 MB
  unsigned short* Vtb   = (unsigned short*)(ws + ((size_t)32 << 20)); // 8 MB
  unsigned short* Mg = Xbf;  // Xbf dead after QKV GEMM

  cvt_bf16_kernel<<<(TOK * D_MODEL / 8 + 255) / 256, 256, 0, stream>>>(X, Xbf, TOK * D_MODEL);
  transpose_cvt_kernel<<<dim3(32, 32, 4), dim3(32, 8), 0, stream>>>(Wq, Wk, Wv, Wo, Wqkvt, Wot);
  gemm128_kernel<0><<<dim3(24, 32), 256, 0, stream>>>(Xbf, Wqkvt, 1024, 3072,
                                                      bq, bk, bv, Qb, Kb, Vtb, nullptr);
  attn_kernel<<<dim3(16, 32), 512, 0, stream>>>(Qb, Kb, Vtb, Mg);
  gemm128_kernel<1><<<dim3(8, 32), 256, 0, stream>>>(Mg, Wot, 1024, 1024,
                                                     bo, nullptr, nullptr,
                                                     nullptr, nullptr, nullptr, out);
}

// Round 6
// 203.711 us; speedup vs baseline: 1.3202x; 1.0262x over previous
//
#include <hip/hip_runtime.h>
#include <hip/hip_bf16.h>

#define D_MODEL 1024
#define HEADS 16
#define HSZ 64
#define BATCH 2
#define SEQ 2048
#define TOK (BATCH*SEQ)   // 4096
#define NT (SEQ/64)       // 32 k-tiles

typedef __attribute__((ext_vector_type(8))) short bf16x8;
typedef __attribute__((ext_vector_type(4))) float f32x4;

// softmax scale folded into Q at QKV epilogue: 1/sqrt(64) * log2(e)
#define QSCALE 0.1803368801111244f
// defer-max threshold in log2 domain (= 8 nats)
#define THR_L2 11.541560327f

static __device__ __forceinline__ unsigned short f2bf(float f) {
  union { float f; unsigned u; } v; v.f = f;
  unsigned r = v.u + 0x7fffu + ((v.u >> 16) & 1u);
  return (unsigned short)(r >> 16);
}

static __device__ __forceinline__ float exp2_fast(float x) {
  float r;
  asm("v_exp_f32 %0, %1" : "=v"(r) : "v"(x));
  return r;
}

static __device__ __forceinline__ unsigned cvt_pk_bf16(float a, float b) {
  unsigned r;
  asm("v_cvt_pk_bf16_f32 %0, %1, %2" : "=v"(r) : "v"(a), "v"(b));
  return r;
}

// byte-offset swizzle: row-major LDS tile with 128B rows (16B granular XOR)
static __device__ __forceinline__ int swz128(int row, int g) {
  return ((row << 7) + (g << 4)) ^ ((row & 7) << 4);
}

// P-tile slot swizzle: 16 8B-slots per 128B row; bijective over 16 lanes
static __device__ __forceinline__ int xs4(int lr) {
  return ((lr & 7) << 1) | (lr >> 3);
}

static __device__ __forceinline__ void load_lds16(const void* g, void* l) {
  __builtin_amdgcn_global_load_lds(
      (const __attribute__((address_space(1))) unsigned*)g,
      (__attribute__((address_space(3))) unsigned*)l, 16, 0, 0);
}

// ---------------- converts ----------------

__global__ void cvt_bf16_kernel(const float* __restrict__ src,
                                unsigned short* __restrict__ dst, int n) {
  int i = (blockIdx.x * blockDim.x + threadIdx.x) * 8;
  if (i >= n) return;
  float4 v0 = *reinterpret_cast<const float4*>(src + i);
  float4 v1 = *reinterpret_cast<const float4*>(src + i + 4);
  ushort4 o0, o1;
  o0.x = f2bf(v0.x); o0.y = f2bf(v0.y); o0.z = f2bf(v0.z); o0.w = f2bf(v0.w);
  o1.x = f2bf(v1.x); o1.y = f2bf(v1.y); o1.z = f2bf(v1.z); o1.w = f2bf(v1.w);
  *reinterpret_cast<ushort4*>(dst + i) = o0;
  *reinterpret_cast<ushort4*>(dst + i + 4) = o1;
}

// W[i][o] fp32 -> Wt[o][i] bf16. z = 0..2: Wq/Wk/Wv into Wqkvt; z = 3: Wo.
__global__ void transpose_cvt_kernel(const float* __restrict__ Wq, const float* __restrict__ Wk,
                                     const float* __restrict__ Wv, const float* __restrict__ Wo,
                                     unsigned short* __restrict__ Wqkvt,
                                     unsigned short* __restrict__ Wot) {
  __shared__ float tile[32][33];
  int m = blockIdx.z;
  const float* src = (m == 0) ? Wq : (m == 1) ? Wk : (m == 2) ? Wv : Wo;
  unsigned short* dst = (m < 3) ? (Wqkvt + (size_t)m * D_MODEL * D_MODEL) : Wot;
  int i0 = blockIdx.y * 32, o0 = blockIdx.x * 32;
  int tx = threadIdx.x, ty = threadIdx.y;
  for (int k = 0; k < 32; k += 8)
    tile[ty + k][tx] = src[(size_t)(i0 + ty + k) * D_MODEL + o0 + tx];
  __syncthreads();
  for (int k = 0; k < 32; k += 8)
    dst[(size_t)(o0 + ty + k) * D_MODEL + i0 + tx] = f2bf(tile[tx][ty + k]);
}

// ---------------- 128x128 bf16 GEMM (m97 structure: global_load_lds, linear LDS)
// C = A[M,K] @ Bt[N,K]^T.  EPI 0: QKV epilogue (bias + Q-prescale + K/V pre-swizzle
// scatter).  EPI 1: fp32 out + bias.

template<int EPI>
__global__ __launch_bounds__(256) void gemm128_kernel(
    const unsigned short* __restrict__ A, const unsigned short* __restrict__ Bt,
    int K, int N,
    const float* __restrict__ b0, const float* __restrict__ b1, const float* __restrict__ b2,
    unsigned short* __restrict__ Qb, unsigned short* __restrict__ Kb,
    unsigned short* __restrict__ Vtb, float* __restrict__ Cout)
{
  __shared__ char As[128 * 64];   // 128 rows x 32 bf16, LINEAR (gload_lds dest)
  __shared__ char Bs[128 * 64];
  // T1: XCD-chunked bijective block swizzle (nwg % 8 == 0 for both uses)
  int gx = gridDim.x;
  int orig = blockIdx.y * gx + blockIdx.x;
  int chunk = (gx * gridDim.y) >> 3;
  int sw = (orig & 7) * chunk + (orig >> 3);
  int m0 = (sw / gx) * 128, n0 = (sw % gx) * 128;
  int tid = threadIdx.x;
  int wv = tid >> 6, l = tid & 63;
  int wm = wv >> 1, wn = wv & 1;
  int lg = l >> 4, lr = l & 15;
  int srow = wv * 32 + (l >> 2);      // staging row (this lane's global row)
  int scol = (l & 3) * 8;             // staging k-offset (elements)

  f32x4 acc[4][4];
#pragma unroll
  for (int i = 0; i < 4; i++)
#pragma unroll
    for (int j = 0; j < 4; j++) acc[i][j] = (f32x4){0.f, 0.f, 0.f, 0.f};

  for (int k0 = 0; k0 < K; k0 += 32) {
    __syncthreads();   // previous iter's fragment reads done
    const unsigned short* ga = A  + (size_t)(m0 + srow) * K + k0 + scol;
    const unsigned short* gb = Bt + (size_t)(n0 + srow) * K + k0 + scol;
    load_lds16(ga,                       As + wv * 2048);
    load_lds16(ga + (size_t)16 * K,      As + wv * 2048 + 1024);
    load_lds16(gb,                       Bs + wv * 2048);
    load_lds16(gb + (size_t)16 * K,      Bs + wv * 2048 + 1024);
    __syncthreads();   // compiler drains vmcnt before barrier -> LDS visible

    bf16x8 af[4], bfv[4];
#pragma unroll
    for (int mi = 0; mi < 4; mi++)
      af[mi] = *reinterpret_cast<const bf16x8*>(As + (wm * 64 + mi * 16 + lr) * 64 + lg * 16);
#pragma unroll
    for (int ni = 0; ni < 4; ni++)
      bfv[ni] = *reinterpret_cast<const bf16x8*>(Bs + (wn * 64 + ni * 16 + lr) * 64 + lg * 16);
#pragma unroll
    for (int mi = 0; mi < 4; mi++)
#pragma unroll
      for (int ni = 0; ni < 4; ni++)
        acc[mi][ni] = __builtin_amdgcn_mfma_f32_16x16x32_bf16(af[mi], bfv[ni], acc[mi][ni], 0, 0, 0);
  }

  // epilogue: D frag mapping col = lane&15, row = (lane>>4)*4 + r
#pragma unroll
  for (int mi = 0; mi < 4; mi++) {
    int gr0 = m0 + wm * 64 + mi * 16 + lg * 4;
#pragma unroll
    for (int ni = 0; ni < 4; ni++) {
      int gc = n0 + wn * 64 + ni * 16 + lr;
      if (EPI == 0) {
        int mat = gc >> 10, o = gc & 1023;
        int hh = o >> 6, d = o & 63;
        const float* bias = (mat == 0) ? b0 : (mat == 1) ? b1 : b2;
        float bv = bias[o];
#pragma unroll
        for (int r = 0; r < 4; r++) {
          int t = gr0 + r;
          int b = t >> 11, s = t & 2047;
          float v = acc[mi][ni][r] + bv;
          if (mat == 0) v *= QSCALE;          // fold softmax scale * log2e into Q
          unsigned short u = f2bf(v);
          size_t head = (size_t)(b * HEADS + hh);
          if (mat == 0)
            Qb[(head * SEQ + s) * HSZ + d] = u;
          else if (mat == 1)   // K pre-swizzled: element idx ^ ((s&7)<<3)
            Kb[((head * SEQ + s) * HSZ + d) ^ ((s & 7) << 3)] = u;
          else                 // V transposed + pre-swizzled: ^ ((d&7)<<3)
            Vtb[(((head * HSZ + d) * SEQ + s)) ^ ((d & 7) << 3)] = u;
        }
      } else {
        float bv = b0[gc];
#pragma unroll
        for (int r = 0; r < 4; r++) {
          int t = gr0 + r;
          Cout[(size_t)t * N + gc] = acc[mi][ni][r] + bv;
        }
      }
    }
  }
}

// ---------------- flash attention ----------------
// grid: (SEQ/128 q-tiles, B*H) XCD-swizzled. block: 512 = 8 waves x 16 q-rows.
// Double-buffered K/V staged via global_load_lds (sources pre-swizzled by the
// QKV epilogue; LDS dest linear; swizzled ds_reads). ONE barrier per tile.
// LDS addresses hoisted PER k2 (the swz128 XOR hits byte bit 6, so "+k2*64"
// would carry for rows with row&4 — that was round 5's bug).

#define KOFF(c) ((c) * 8192)
#define VOFF(c) (16384 + (c) * 8192)
#define POFF(w) (32768 + (w) * 2048)

__global__ __launch_bounds__(512, 4) void attn_kernel(
    const unsigned short* __restrict__ Qb, const unsigned short* __restrict__ Kb,
    const unsigned short* __restrict__ Vtb, unsigned short* __restrict__ Mg)
{
  __shared__ char lds[49152];   // K[2][8K] | V[2][8K] | P[8][2K]

  // XCD-chunked swizzle: 512 blocks -> 64 consecutive per XCD -> 4 heads/XCD
  int orig = blockIdx.y * 16 + blockIdx.x;
  int swzb = (orig & 7) * 64 + (orig >> 3);
  int bh = swzb >> 4;
  int q0 = (swzb & 15) * 128;
  int b = bh >> 4, h = bh & 15;
  int tid = threadIdx.x, w = tid >> 6, l = tid & 63;
  int lg = l >> 4, lr = l & 15;
  const unsigned short* Qh = Qb + (size_t)bh * SEQ * HSZ;
  const char* Kg = (const char*)(Kb + (size_t)bh * SEQ * HSZ) + (size_t)tid * 16;
  const char* Vg = (const char*)(Vtb + (size_t)bh * HSZ * SEQ)
                   + (size_t)(tid >> 3) * (SEQ * 2) + (tid & 7) * 16;

  // hoisted LDS addresses: one base per k2 (group g = k2*4+lg)
  int dsb[2] = { swz128(lr, lg), swz128(lr, lg + 4) };
  int pwa[4], paa[4];
#pragma unroll
  for (int ni = 0; ni < 4; ni++)
    pwa[ni] = POFF(w) + (lr << 7) + ((((ni << 2) + lg) ^ xs4(lr)) << 3);
#pragma unroll
  for (int k2 = 0; k2 < 2; k2++)
#pragma unroll
    for (int hh = 0; hh < 2; hh++)
      paa[k2 * 2 + hh] = POFF(w) + (lr << 7) + (((k2 * 8 + lg * 2 + hh) ^ xs4(lr)) << 3);

  // Q as MFMA B-fragments (prescaled by QSCALE at QKV epilogue)
  bf16x8 qf2[2];
#pragma unroll
  for (int k2 = 0; k2 < 2; k2++)
    qf2[k2] = *reinterpret_cast<const bf16x8*>(
        Qh + (size_t)(q0 + w * 16 + lr) * HSZ + k2 * 32 + lg * 8);

  f32x4 of[4];
  f32x4 lones = (f32x4){0.f, 0.f, 0.f, 0.f};
#pragma unroll
  for (int ni = 0; ni < 4; ni++) of[ni] = (f32x4){0.f, 0.f, 0.f, 0.f};
  float m_r = -1e30f;

  bf16x8 vone;
#pragma unroll
  for (int j = 0; j < 8; j++) vone[j] = (short)0x3F80;   // bf16 1.0

  // staging: one 16B gload_lds for K + one for V per thread per tile
  auto stage = [&](int t, int nb) {
    if (t < NT) {
      load_lds16(Kg + (size_t)t * 8192, lds + KOFF(nb) + w * 1024);
      load_lds16(Vg + (size_t)t * 128,  lds + VOFF(nb) + w * 1024);
    }
  };

  auto body = [&](int t, int cur) {
    stage(t + 1, cur ^ 1);   // fire-and-forget; lands before this tile's barrier

    // S = K Q (swapped): lane holds S[sk = ni*16+lg*4+r][q = lr]
    f32x4 sf[4];
#pragma unroll
    for (int ni = 0; ni < 4; ni++) {
      sf[ni] = (f32x4){0.f, 0.f, 0.f, 0.f};
#pragma unroll
      for (int k2 = 0; k2 < 2; k2++) {
        bf16x8 kf = *reinterpret_cast<const bf16x8*>(lds + dsb[k2] + KOFF(cur) + ni * 2048);
        sf[ni] = __builtin_amdgcn_mfma_f32_16x16x32_bf16(kf, qf2[k2], sf[ni], 0, 0, 0);
      }
    }

    // local max over the 16 in-lane k-values for q-col lr
    float lm = fmaxf(fmaxf(fmaxf(sf[0][0], sf[0][1]), fmaxf(sf[0][2], sf[0][3])),
                     fmaxf(fmaxf(sf[1][0], sf[1][1]), fmaxf(sf[1][2], sf[1][3])));
    lm = fmaxf(lm,
         fmaxf(fmaxf(fmaxf(sf[2][0], sf[2][1]), fmaxf(sf[2][2], sf[2][3])),
               fmaxf(fmaxf(sf[3][0], sf[3][1]), fmaxf(sf[3][2], sf[3][3]))));

    // defer-max: full reduce + rescale only when a row grew past THR
    if (__any(lm > m_r + THR_L2)) {
      float vm = fmaxf(lm, __shfl_xor(lm, 16));
      vm = fmaxf(vm, __shfl_xor(vm, 32));
      float mn = fmaxf(m_r, vm);
      float al = exp2_fast(m_r - mn);
      m_r = mn;
#pragma unroll
      for (int r = 0; r < 4; r++) {
        float a = __shfl(al, lg * 4 + r, 16);
        lones[r] *= a;
#pragma unroll
        for (int ni = 0; ni < 4; ni++) of[ni][r] *= a;
      }
    }

    // P = exp2(S - m); pack; write per-wave P tile (addresses hoisted)
#pragma unroll
    for (int ni = 0; ni < 4; ni++) {
      uint2 pw;
      pw.x = cvt_pk_bf16(exp2_fast(sf[ni][0] - m_r), exp2_fast(sf[ni][1] - m_r));
      pw.y = cvt_pk_bf16(exp2_fast(sf[ni][2] - m_r), exp2_fast(sf[ni][3] - m_r));
      *reinterpret_cast<uint2*>(lds + pwa[ni]) = pw;
    }

    // assemble PV A-fragments
    bf16x8 pa[2];
#pragma unroll
    for (int k2 = 0; k2 < 2; k2++) {
      uint2 lo = *reinterpret_cast<const uint2*>(lds + paa[k2 * 2]);
      uint2 hi = *reinterpret_cast<const uint2*>(lds + paa[k2 * 2 + 1]);
      int4 tt = {(int)lo.x, (int)lo.y, (int)hi.x, (int)hi.y};
      pa[k2] = *reinterpret_cast<bf16x8*>(&tt);
    }

    // O += P V ; l += P 1
    __builtin_amdgcn_s_setprio(1);
#pragma unroll
    for (int k2 = 0; k2 < 2; k2++)
      lones = __builtin_amdgcn_mfma_f32_16x16x32_bf16(pa[k2], vone, lones, 0, 0, 0);
#pragma unroll
    for (int ni = 0; ni < 4; ni++)
#pragma unroll
      for (int k2 = 0; k2 < 2; k2++) {
        bf16x8 vf = *reinterpret_cast<const bf16x8*>(lds + dsb[k2] + VOFF(cur) + ni * 2048);
        of[ni] = __builtin_amdgcn_mfma_f32_16x16x32_bf16(pa[k2], vf, of[ni], 0, 0, 0);
      }
    __builtin_amdgcn_s_setprio(0);

    __syncthreads();   // drains vmcnt (next tile staged) + lgkm; ONE barrier/tile
  };

  stage(0, 0);
  __syncthreads();
  for (int kt = 0; kt < NT; kt += 2) {
    body(kt, 0);
    body(kt + 1, 1);
  }

  // epilogue: merged[b][q][h*64+d], q = q0+w*16+lg*4+r, d = ni*16+lr
#pragma unroll
  for (int r = 0; r < 4; r++) {
    float inv = 1.0f / lones[r];
    int q = q0 + w * 16 + lg * 4 + r;
#pragma unroll
    for (int ni = 0; ni < 4; ni++) {
      int dm = h * 64 + ni * 16 + lr;
      Mg[(size_t)(b * SEQ + q) * D_MODEL + dm] = f2bf(of[ni][r] * inv);
    }
  }
}

// ---------------- launch ----------------

extern "C" void kernel_launch(void* const* d_in, const int* in_sizes, int n_in,
                              void* d_out, int out_size, void* d_ws, size_t ws_size,
                              hipStream_t stream) {
  const float* X  = (const float*)d_in[0];
  const float* Wq = (const float*)d_in[1];
  const float* bq = (const float*)d_in[2];
  const float* Wk = (const float*)d_in[3];
  const float* bk = (const float*)d_in[4];
  const float* Wv = (const float*)d_in[5];
  const float* bv = (const float*)d_in[6];
  const float* Wo = (const float*)d_in[7];
  const float* bo = (const float*)d_in[8];
  float* out = (float*)d_out;

  char* ws = (char*)d_ws;
  unsigned short* Xbf   = (unsigned short*)(ws);                      // 8 MB (reused as merged)
  unsigned short* Wqkvt = (unsigned short*)(ws + ((size_t)8  << 20)); // 6 MB
  unsigned short* Wot   = (unsigned short*)(ws + ((size_t)14 << 20)); // 2 MB
  unsigned short* Qb    = (unsigned short*)(ws + ((size_t)16 << 20)); // 8 MB
  unsigned short* Kb    = (unsigned short*)(ws + ((size_t)24 << 20)); // 8 MB
  unsigned short* Vtb   = (unsigned short*)(ws + ((size_t)32 << 20)); // 8 MB
  unsigned short* Mg = Xbf;  // Xbf dead after QKV GEMM

  cvt_bf16_kernel<<<(TOK * D_MODEL / 8 + 255) / 256, 256, 0, stream>>>(X, Xbf, TOK * D_MODEL);
  transpose_cvt_kernel<<<dim3(32, 32, 4), dim3(32, 8), 0, stream>>>(Wq, Wk, Wv, Wo, Wqkvt, Wot);
  gemm128_kernel<0><<<dim3(24, 32), 256, 0, stream>>>(Xbf, Wqkvt, 1024, 3072,
                                                      bq, bk, bv, Qb, Kb, Vtb, nullptr);
  attn_kernel<<<dim3(16, 32), 512, 0, stream>>>(Qb, Kb, Vtb, Mg);
  gemm128_kernel<1><<<dim3(8, 32), 256, 0, stream>>>(Mg, Wot, 1024, 1024,
                                                     bo, nullptr, nullptr,
                                                     nullptr, nullptr, nullptr, out);
}

// Round 9
// 183.150 us; speedup vs baseline: 1.4684x; 1.1123x over previous
//
#include <hip/hip_runtime.h>
#include <hip/hip_bf16.h>

#define D_MODEL 1024
#define HEADS 16
#define HSZ 64
#define BATCH 2
#define SEQ 2048
#define TOK (BATCH*SEQ)   // 4096
#define NT (SEQ/64)       // 32 k-tiles

typedef __attribute__((ext_vector_type(8))) short bf16x8;
typedef __attribute__((ext_vector_type(4))) float f32x4;

// softmax scale folded into Q at QKV epilogue: 1/sqrt(64) * log2(e)
#define QSCALE 0.1803368801111244f
// defer-max threshold in log2 domain (= 8 nats)
#define THR_L2 11.541560327f

static __device__ __forceinline__ unsigned short f2bf(float f) {
  union { float f; unsigned u; } v; v.f = f;
  unsigned r = v.u + 0x7fffu + ((v.u >> 16) & 1u);
  return (unsigned short)(r >> 16);
}

static __device__ __forceinline__ float exp2_fast(float x) {
  float r;
  asm("v_exp_f32 %0, %1" : "=v"(r) : "v"(x));
  return r;
}

static __device__ __forceinline__ unsigned cvt_pk_bf16(float a, float b) {
  unsigned r;
  asm("v_cvt_pk_bf16_f32 %0, %1, %2" : "=v"(r) : "v"(a), "v"(b));
  return r;
}

// byte-offset swizzle: row-major LDS tile with 128B rows (16B granular XOR)
static __device__ __forceinline__ int swz128(int row, int g) {
  return ((row << 7) + (g << 4)) ^ ((row & 7) << 4);
}

// P-tile slot swizzle: 16 8B-slots per 128B row; bijective over 16 lanes
static __device__ __forceinline__ int xs4(int lr) {
  return ((lr & 7) << 1) | (lr >> 3);
}

static __device__ __forceinline__ void load_lds16(const void* g, void* l) {
  __builtin_amdgcn_global_load_lds(
      (const __attribute__((address_space(1))) unsigned*)g,
      (__attribute__((address_space(3))) unsigned*)l, 16, 0, 0);
}

// ---------------- converts ----------------

__global__ void cvt_bf16_kernel(const float* __restrict__ src,
                                unsigned short* __restrict__ dst, int n) {
  int i = (blockIdx.x * blockDim.x + threadIdx.x) * 8;
  if (i >= n) return;
  float4 v0 = *reinterpret_cast<const float4*>(src + i);
  float4 v1 = *reinterpret_cast<const float4*>(src + i + 4);
  ushort4 o0, o1;
  o0.x = f2bf(v0.x); o0.y = f2bf(v0.y); o0.z = f2bf(v0.z); o0.w = f2bf(v0.w);
  o1.x = f2bf(v1.x); o1.y = f2bf(v1.y); o1.z = f2bf(v1.z); o1.w = f2bf(v1.w);
  *reinterpret_cast<ushort4*>(dst + i) = o0;
  *reinterpret_cast<ushort4*>(dst + i + 4) = o1;
}

// W[i][o] fp32 -> Wt[o][i] bf16. z = 0..2: Wq/Wk/Wv into Wqkvt; z = 3: Wo.
__global__ void transpose_cvt_kernel(const float* __restrict__ Wq, const float* __restrict__ Wk,
                                     const float* __restrict__ Wv, const float* __restrict__ Wo,
                                     unsigned short* __restrict__ Wqkvt,
                                     unsigned short* __restrict__ Wot) {
  __shared__ float tile[32][33];
  int m = blockIdx.z;
  const float* src = (m == 0) ? Wq : (m == 1) ? Wk : (m == 2) ? Wv : Wo;
  unsigned short* dst = (m < 3) ? (Wqkvt + (size_t)m * D_MODEL * D_MODEL) : Wot;
  int i0 = blockIdx.y * 32, o0 = blockIdx.x * 32;
  int tx = threadIdx.x, ty = threadIdx.y;
  for (int k = 0; k < 32; k += 8)
    tile[ty + k][tx] = src[(size_t)(i0 + ty + k) * D_MODEL + o0 + tx];
  __syncthreads();
  for (int k = 0; k < 32; k += 8)
    dst[(size_t)(o0 + ty + k) * D_MODEL + i0 + tx] = f2bf(tile[tx][ty + k]);
}

// ---------------- QKV GEMM: 128x128 tile, BK=64, global_load_lds staging ----
// LDS rows are 128B -> 3-bit chunk-XOR swizzle (g' = g ^ (row&7)), applied as
// pre-swizzled GLOBAL source (gload_lds dest must stay linear) + XOR'd ds_read.
// Epilogue: Q (bias+QSCALE), K (bias, pre-swizzled), V (bias, single-pass
// LDS-bounce transpose: wm=0 waves->As, wm=1 waves->Bs, one barrier, then
// coalesced 16B stores into the pre-swizzled Vt layout).

__global__ __launch_bounds__(256, 3) void gemm_qkv_kernel(
    const unsigned short* __restrict__ A, const unsigned short* __restrict__ Bt,
    const float* __restrict__ b0, const float* __restrict__ b1, const float* __restrict__ b2,
    unsigned short* __restrict__ Qb, unsigned short* __restrict__ Kb,
    unsigned short* __restrict__ Vtb)
{
  __shared__ char As[16384];   // 128 rows x 64 shorts (128B rows)
  __shared__ char Bs[16384];
  const int K = D_MODEL;
  // T1: XCD-chunked bijective block swizzle (768 % 8 == 0)
  int gx = gridDim.x;
  int orig = blockIdx.y * gx + blockIdx.x;
  int chunk = (gx * gridDim.y) >> 3;
  int sw = (orig & 7) * chunk + (orig >> 3);
  int m0 = (sw / gx) * 128, n0 = (sw % gx) * 128;
  int tid = threadIdx.x;
  int wv = tid >> 6, l = tid & 63;
  int wm = wv >> 1, wn = wv & 1;
  int lg = l >> 4, lr = l & 15;

  // staging: lane covers row (wv*32 + i*8 + (l>>3)), chunk (l&7); source chunk
  // pre-swizzled by row&7 = l>>3
  int sr = wv * 32 + (l >> 3);
  int csw = ((l & 7) ^ (l >> 3)) << 3;   // shorts
  const unsigned short* gaA = A  + (size_t)(m0 + sr) * K + csw;
  const unsigned short* gaB = Bt + (size_t)(n0 + sr) * K + csw;

  // fragment read byte-offsets: chunk g' = (kk*4+lg) ^ (lr&7)  (3-bit XOR, no carry)
  int gk0 = ((lg       ^ (lr & 7)) << 4);
  int gk1 = (((4 + lg) ^ (lr & 7)) << 4);
  int arow = (wm * 64 + lr) * 128;
  int brow = (wn * 64 + lr) * 128;

  f32x4 acc[4][4];
#pragma unroll
  for (int i = 0; i < 4; i++)
#pragma unroll
    for (int j = 0; j < 4; j++) acc[i][j] = (f32x4){0.f, 0.f, 0.f, 0.f};

  for (int k0 = 0; k0 < K; k0 += 64) {
    __syncthreads();
#pragma unroll
    for (int i = 0; i < 4; i++) {
      load_lds16(gaA + k0 + i * 8 * K, As + wv * 4096 + i * 1024);
      load_lds16(gaB + k0 + i * 8 * K, Bs + wv * 4096 + i * 1024);
    }
    __syncthreads();

    bf16x8 af0[4], af1[4], bf0[4], bf1[4];
#pragma unroll
    for (int mi = 0; mi < 4; mi++) {
      af0[mi] = *reinterpret_cast<const bf16x8*>(As + arow + mi * 2048 + gk0);
      af1[mi] = *reinterpret_cast<const bf16x8*>(As + arow + mi * 2048 + gk1);
    }
#pragma unroll
    for (int ni = 0; ni < 4; ni++) {
      bf0[ni] = *reinterpret_cast<const bf16x8*>(Bs + brow + ni * 2048 + gk0);
      bf1[ni] = *reinterpret_cast<const bf16x8*>(Bs + brow + ni * 2048 + gk1);
    }
#pragma unroll
    for (int mi = 0; mi < 4; mi++)
#pragma unroll
      for (int ni = 0; ni < 4; ni++) {
        acc[mi][ni] = __builtin_amdgcn_mfma_f32_16x16x32_bf16(af0[mi], bf0[ni], acc[mi][ni], 0, 0, 0);
        acc[mi][ni] = __builtin_amdgcn_mfma_f32_16x16x32_bf16(af1[mi], bf1[ni], acc[mi][ni], 0, 0, 0);
      }
  }

  if (n0 < 2048) {
    // ---- Q / K scalar epilogue ----
#pragma unroll
    for (int mi = 0; mi < 4; mi++) {
      int gr0 = m0 + wm * 64 + mi * 16 + lg * 4;
#pragma unroll
      for (int ni = 0; ni < 4; ni++) {
        int gc = n0 + wn * 64 + ni * 16 + lr;
        int mat = gc >> 10, o = gc & 1023;
        int hh = o >> 6, d = o & 63;
        float bv = (mat == 0) ? b0[o] : b1[o];
#pragma unroll
        for (int r = 0; r < 4; r++) {
          int t = gr0 + r;
          int b = t >> 11, s = t & 2047;
          float v = acc[mi][ni][r] + bv;
          if (mat == 0) v *= QSCALE;
          unsigned short u = f2bf(v);
          size_t head = (size_t)(b * HEADS + hh);
          if (mat == 0)
            Qb[(head * SEQ + s) * HSZ + d] = u;
          else                 // K pre-swizzled: element idx ^ ((s&7)<<3)
            Kb[((head * SEQ + s) * HSZ + d) ^ ((s & 7) << 3)] = u;
        }
      }
    }
  } else {
    // ---- V epilogue: single-pass LDS-bounce transpose ----
    // wm=0 waves own s-rows 0..63 -> As; wm=1 waves own s-rows 64..127 -> Bs.
    // All 4 waves write simultaneously to disjoint buffers; ONE barrier; then
    // all threads read back both buffers with coalesced 16B global stores.
    int bglob = m0 >> 11;
    int hh0 = (n0 - 2048) >> 6;
    float bvv[4];
#pragma unroll
    for (int ni = 0; ni < 4; ni++) bvv[ni] = b2[(n0 - 2048) + wn * 64 + ni * 16 + lr];

    __syncthreads();   // all fragment ds_reads of the main loop done
    {
      char* dstbuf = (wm == 0) ? As : Bs;
      // col-major [col cc][64 rows], 4 rows packed per 8B; slot-XOR by (cc&7)
#pragma unroll
      for (int mi = 0; mi < 4; mi++) {
        int lrow = mi * 16 + lg * 4;
#pragma unroll
        for (int ni = 0; ni < 4; ni++) {
          int cc = wn * 64 + ni * 16 + lr;
          uint2 pw;
          pw.x = cvt_pk_bf16(acc[mi][ni][0] + bvv[ni], acc[mi][ni][1] + bvv[ni]);
          pw.y = cvt_pk_bf16(acc[mi][ni][2] + bvv[ni], acc[mi][ni][3] + bvv[ni]);
          int ba = (cc * 128 + lrow * 2) ^ ((cc & 7) << 3);
          *reinterpret_cast<uint2*>(dstbuf + ba) = pw;
        }
      }
    }
    __syncthreads();
    // read-back: 8 lanes per col, each 16B = 8 tokens -> 128B-contiguous global
    int ck = tid & 7;
#pragma unroll
    for (int pass = 0; pass < 4; ++pass) {
      int cc = (tid >> 3) + pass * 32;
      int x = cc & 7;
      int d = cc & 63, hh = hh0 + (cc >> 6);
      size_t rowbase = (((size_t)(bglob * HEADS + hh)) * HSZ + d) * SEQ;
      int slo = ((ck * 2)     ^ x) << 3;
      int shi = ((ck * 2 + 1) ^ x) << 3;
      {
        uint2 lo = *reinterpret_cast<const uint2*>(As + (cc << 7) + slo);
        uint2 hi = *reinterpret_cast<const uint2*>(As + (cc << 7) + shi);
        int s = (m0 & 2047) + ck * 8;
        size_t idx = (rowbase + s) ^ ((d & 7) << 3);
        uint4 val = {lo.x, lo.y, hi.x, hi.y};
        *reinterpret_cast<uint4*>(Vtb + idx) = val;
      }
      {
        uint2 lo = *reinterpret_cast<const uint2*>(Bs + (cc << 7) + slo);
        uint2 hi = *reinterpret_cast<const uint2*>(Bs + (cc << 7) + shi);
        int s = (m0 & 2047) + 64 + ck * 8;
        size_t idx = (rowbase + s) ^ ((d & 7) << 3);
        uint4 val = {lo.x, lo.y, hi.x, hi.y};
        *reinterpret_cast<uint4*>(Vtb + idx) = val;
      }
    }
  }
}

// ---------------- proj GEMM: 128x64 tile, BK=64 (2 blocks/CU) ----------------

__global__ __launch_bounds__(256, 2) void gemm_proj_kernel(
    const unsigned short* __restrict__ A, const unsigned short* __restrict__ Bt,
    const float* __restrict__ bias, float* __restrict__ Cout)
{
  __shared__ char As[16384];   // 128 x 64 shorts
  __shared__ char Bs[8192];    // 64 x 64 shorts
  const int K = D_MODEL;
  int gx = gridDim.x;   // 16
  int orig = blockIdx.y * gx + blockIdx.x;
  int chunk = (gx * gridDim.y) >> 3;
  int sw = (orig & 7) * chunk + (orig >> 3);
  int m0 = (sw / gx) * 128, n0 = (sw % gx) * 64;
  int tid = threadIdx.x;
  int wv = tid >> 6, l = tid & 63;
  int wm = wv >> 1, wn = wv & 1;
  int lg = l >> 4, lr = l & 15;

  int srA = wv * 32 + (l >> 3);
  int srB = wv * 16 + (l >> 3);
  int csw = ((l & 7) ^ (l >> 3)) << 3;
  const unsigned short* gaA = A  + (size_t)(m0 + srA) * K + csw;
  const unsigned short* gaB = Bt + (size_t)(n0 + srB) * K + csw;

  int gk0 = ((lg       ^ (lr & 7)) << 4);
  int gk1 = (((4 + lg) ^ (lr & 7)) << 4);
  int arow = (wm * 64 + lr) * 128;
  int brow = (wn * 32 + lr) * 128;

  f32x4 acc[4][2];
#pragma unroll
  for (int i = 0; i < 4; i++)
#pragma unroll
    for (int j = 0; j < 2; j++) acc[i][j] = (f32x4){0.f, 0.f, 0.f, 0.f};

  for (int k0 = 0; k0 < K; k0 += 64) {
    __syncthreads();
#pragma unroll
    for (int i = 0; i < 4; i++)
      load_lds16(gaA + k0 + i * 8 * K, As + wv * 4096 + i * 1024);
#pragma unroll
    for (int i = 0; i < 2; i++)
      load_lds16(gaB + k0 + i * 8 * K, Bs + wv * 2048 + i * 1024);
    __syncthreads();

    bf16x8 af0[4], af1[4], bf0[2], bf1[2];
#pragma unroll
    for (int mi = 0; mi < 4; mi++) {
      af0[mi] = *reinterpret_cast<const bf16x8*>(As + arow + mi * 2048 + gk0);
      af1[mi] = *reinterpret_cast<const bf16x8*>(As + arow + mi * 2048 + gk1);
    }
#pragma unroll
    for (int ni = 0; ni < 2; ni++) {
      bf0[ni] = *reinterpret_cast<const bf16x8*>(Bs + brow + ni * 2048 + gk0);
      bf1[ni] = *reinterpret_cast<const bf16x8*>(Bs + brow + ni * 2048 + gk1);
    }
#pragma unroll
    for (int mi = 0; mi < 4; mi++)
#pragma unroll
      for (int ni = 0; ni < 2; ni++) {
        acc[mi][ni] = __builtin_amdgcn_mfma_f32_16x16x32_bf16(af0[mi], bf0[ni], acc[mi][ni], 0, 0, 0);
        acc[mi][ni] = __builtin_amdgcn_mfma_f32_16x16x32_bf16(af1[mi], bf1[ni], acc[mi][ni], 0, 0, 0);
      }
  }

#pragma unroll
  for (int mi = 0; mi < 4; mi++) {
    int gr0 = m0 + wm * 64 + mi * 16 + lg * 4;
#pragma unroll
    for (int ni = 0; ni < 2; ni++) {
      int gc = n0 + wn * 32 + ni * 16 + lr;
      float bv = bias[gc];
#pragma unroll
      for (int r = 0; r < 4; r++)
        Cout[(size_t)(gr0 + r) * D_MODEL + gc] = acc[mi][ni][r] + bv;
    }
  }
}

// ---------------- flash attention (unchanged from round 6) ----------------

#define KOFF(c) ((c) * 8192)
#define VOFF(c) (16384 + (c) * 8192)
#define POFF(w) (32768 + (w) * 2048)

__global__ __launch_bounds__(512, 4) void attn_kernel(
    const unsigned short* __restrict__ Qb, const unsigned short* __restrict__ Kb,
    const unsigned short* __restrict__ Vtb, unsigned short* __restrict__ Mg)
{
  __shared__ char lds[49152];   // K[2][8K] | V[2][8K] | P[8][2K]

  int orig = blockIdx.y * 16 + blockIdx.x;
  int swzb = (orig & 7) * 64 + (orig >> 3);
  int bh = swzb >> 4;
  int q0 = (swzb & 15) * 128;
  int b = bh >> 4, h = bh & 15;
  int tid = threadIdx.x, w = tid >> 6, l = tid & 63;
  int lg = l >> 4, lr = l & 15;
  const unsigned short* Qh = Qb + (size_t)bh * SEQ * HSZ;
  const char* Kg = (const char*)(Kb + (size_t)bh * SEQ * HSZ) + (size_t)tid * 16;
  const char* Vg = (const char*)(Vtb + (size_t)bh * HSZ * SEQ)
                   + (size_t)(tid >> 3) * (SEQ * 2) + (tid & 7) * 16;

  int dsb[2] = { swz128(lr, lg), swz128(lr, lg + 4) };
  int pwa[4], paa[4];
#pragma unroll
  for (int ni = 0; ni < 4; ni++)
    pwa[ni] = POFF(w) + (lr << 7) + ((((ni << 2) + lg) ^ xs4(lr)) << 3);
#pragma unroll
  for (int k2 = 0; k2 < 2; k2++)
#pragma unroll
    for (int hh = 0; hh < 2; hh++)
      paa[k2 * 2 + hh] = POFF(w) + (lr << 7) + (((k2 * 8 + lg * 2 + hh) ^ xs4(lr)) << 3);

  bf16x8 qf2[2];
#pragma unroll
  for (int k2 = 0; k2 < 2; k2++)
    qf2[k2] = *reinterpret_cast<const bf16x8*>(
        Qh + (size_t)(q0 + w * 16 + lr) * HSZ + k2 * 32 + lg * 8);

  f32x4 of[4];
  f32x4 lones = (f32x4){0.f, 0.f, 0.f, 0.f};
#pragma unroll
  for (int ni = 0; ni < 4; ni++) of[ni] = (f32x4){0.f, 0.f, 0.f, 0.f};
  float m_r = -1e30f;

  bf16x8 vone;
#pragma unroll
  for (int j = 0; j < 8; j++) vone[j] = (short)0x3F80;   // bf16 1.0

  auto stage = [&](int t, int nb) {
    if (t < NT) {
      load_lds16(Kg + (size_t)t * 8192, lds + KOFF(nb) + w * 1024);
      load_lds16(Vg + (size_t)t * 128,  lds + VOFF(nb) + w * 1024);
    }
  };

  auto body = [&](int t, int cur) {
    stage(t + 1, cur ^ 1);

    f32x4 sf[4];
#pragma unroll
    for (int ni = 0; ni < 4; ni++) {
      sf[ni] = (f32x4){0.f, 0.f, 0.f, 0.f};
#pragma unroll
      for (int k2 = 0; k2 < 2; k2++) {
        bf16x8 kf = *reinterpret_cast<const bf16x8*>(lds + dsb[k2] + KOFF(cur) + ni * 2048);
        sf[ni] = __builtin_amdgcn_mfma_f32_16x16x32_bf16(kf, qf2[k2], sf[ni], 0, 0, 0);
      }
    }

    float lm = fmaxf(fmaxf(fmaxf(sf[0][0], sf[0][1]), fmaxf(sf[0][2], sf[0][3])),
                     fmaxf(fmaxf(sf[1][0], sf[1][1]), fmaxf(sf[1][2], sf[1][3])));
    lm = fmaxf(lm,
         fmaxf(fmaxf(fmaxf(sf[2][0], sf[2][1]), fmaxf(sf[2][2], sf[2][3])),
               fmaxf(fmaxf(sf[3][0], sf[3][1]), fmaxf(sf[3][2], sf[3][3]))));

    if (__any(lm > m_r + THR_L2)) {
      float vm = fmaxf(lm, __shfl_xor(lm, 16));
      vm = fmaxf(vm, __shfl_xor(vm, 32));
      float mn = fmaxf(m_r, vm);
      float al = exp2_fast(m_r - mn);
      m_r = mn;
#pragma unroll
      for (int r = 0; r < 4; r++) {
        float a = __shfl(al, lg * 4 + r, 16);
        lones[r] *= a;
#pragma unroll
        for (int ni = 0; ni < 4; ni++) of[ni][r] *= a;
      }
    }

#pragma unroll
    for (int ni = 0; ni < 4; ni++) {
      uint2 pw;
      pw.x = cvt_pk_bf16(exp2_fast(sf[ni][0] - m_r), exp2_fast(sf[ni][1] - m_r));
      pw.y = cvt_pk_bf16(exp2_fast(sf[ni][2] - m_r), exp2_fast(sf[ni][3] - m_r));
      *reinterpret_cast<uint2*>(lds + pwa[ni]) = pw;
    }

    bf16x8 pa[2];
#pragma unroll
    for (int k2 = 0; k2 < 2; k2++) {
      uint2 lo = *reinterpret_cast<const uint2*>(lds + paa[k2 * 2]);
      uint2 hi = *reinterpret_cast<const uint2*>(lds + paa[k2 * 2 + 1]);
      int4 tt = {(int)lo.x, (int)lo.y, (int)hi.x, (int)hi.y};
      pa[k2] = *reinterpret_cast<bf16x8*>(&tt);
    }

    __builtin_amdgcn_s_setprio(1);
#pragma unroll
    for (int k2 = 0; k2 < 2; k2++)
      lones = __builtin_amdgcn_mfma_f32_16x16x32_bf16(pa[k2], vone, lones, 0, 0, 0);
#pragma unroll
    for (int ni = 0; ni < 4; ni++)
#pragma unroll
      for (int k2 = 0; k2 < 2; k2++) {
        bf16x8 vf = *reinterpret_cast<const bf16x8*>(lds + dsb[k2] + VOFF(cur) + ni * 2048);
        of[ni] = __builtin_amdgcn_mfma_f32_16x16x32_bf16(pa[k2], vf, of[ni], 0, 0, 0);
      }
    __builtin_amdgcn_s_setprio(0);

    __syncthreads();
  };

  stage(0, 0);
  __syncthreads();
  for (int kt = 0; kt < NT; kt += 2) {
    body(kt, 0);
    body(kt + 1, 1);
  }

#pragma unroll
  for (int r = 0; r < 4; r++) {
    float inv = 1.0f / lones[r];
    int q = q0 + w * 16 + lg * 4 + r;
#pragma unroll
    for (int ni = 0; ni < 4; ni++) {
      int dm = h * 64 + ni * 16 + lr;
      Mg[(size_t)(b * SEQ + q) * D_MODEL + dm] = f2bf(of[ni][r] * inv);
    }
  }
}

// ---------------- launch ----------------

extern "C" void kernel_launch(void* const* d_in, const int* in_sizes, int n_in,
                              void* d_out, int out_size, void* d_ws, size_t ws_size,
                              hipStream_t stream) {
  const float* X  = (const float*)d_in[0];
  const float* Wq = (const float*)d_in[1];
  const float* bq = (const float*)d_in[2];
  const float* Wk = (const float*)d_in[3];
  const float* bk = (const float*)d_in[4];
  const float* Wv = (const float*)d_in[5];
  const float* bv = (const float*)d_in[6];
  const float* Wo = (const float*)d_in[7];
  const float* bo = (const float*)d_in[8];
  float* out = (float*)d_out;

  char* ws = (char*)d_ws;
  unsigned short* Xbf   = (unsigned short*)(ws);                      // 8 MB (reused as merged)
  unsigned short* Wqkvt = (unsigned short*)(ws + ((size_t)8  << 20)); // 6 MB
  unsigned short* Wot   = (unsigned short*)(ws + ((size_t)14 << 20)); // 2 MB
  unsigned short* Qb    = (unsigned short*)(ws + ((size_t)16 << 20)); // 8 MB
  unsigned short* Kb    = (unsigned short*)(ws + ((size_t)24 << 20)); // 8 MB
  unsigned short* Vtb   = (unsigned short*)(ws + ((size_t)32 << 20)); // 8 MB
  unsigned short* Mg = Xbf;  // Xbf dead after QKV GEMM

  cvt_bf16_kernel<<<(TOK * D_MODEL / 8 + 255) / 256, 256, 0, stream>>>(X, Xbf, TOK * D_MODEL);
  transpose_cvt_kernel<<<dim3(32, 32, 4), dim3(32, 8), 0, stream>>>(Wq, Wk, Wv, Wo, Wqkvt, Wot);
  gemm_qkv_kernel<<<dim3(24, 32), 256, 0, stream>>>(Xbf, Wqkvt, bq, bk, bv, Qb, Kb, Vtb);
  attn_kernel<<<dim3(16, 32), 512, 0, stream>>>(Qb, Kb, Vtb, Mg);
  gemm_proj_kernel<<<dim3(16, 32), 256, 0, stream>>>(Mg, Wot, bo, out);
}